// Round 2
// baseline (342.563 us; speedup 1.0000x reference)
//
#include <hip/hip_runtime.h>
#include <math.h>

// Problem constants (from reference): B=256, S=128, E=1024
#define Bb 256
#define Ss 128
#define Ee 1024
#define BK 64
#define APAD 72   // 64 + 8 elements pad -> 144B row stride (2-way bank alias = free)

typedef __bf16 bf16x8 __attribute__((ext_vector_type(8)));
typedef float f32x4 __attribute__((ext_vector_type(4)));

typedef __attribute__((address_space(3))) unsigned int lds_u32;
typedef __attribute__((address_space(1))) unsigned int glb_u32;

static __device__ __forceinline__ unsigned short f2bf(float f) {
    unsigned int u = __float_as_uint(f);
    u += 0x7FFFu + ((u >> 16) & 1u);
    return (unsigned short)(u >> 16);
}

// ---------------------------------------------------------------------------
// Kernel 1: convert W [E,E] f32 -> bf16 (2 MB in ws).
__global__ void convW_kernel(const float* __restrict__ W, unsigned short* __restrict__ Wb) {
    int i = blockIdx.x * blockDim.x + threadIdx.x;
    float4 v = reinterpret_cast<const float4*>(W)[i];
    ushort4 o;
    o.x = f2bf(v.x); o.y = f2bf(v.y); o.z = f2bf(v.z); o.w = f2bf(v.w);
    reinterpret_cast<ushort4*>(Wb)[i] = o;
}

// ---------------------------------------------------------------------------
// Kernel 2: fused scores GEMM, double-buffered + XOR-swizzled B.
// Block (ft, b): partial scores for bag b over f-cols [ft*128, ft*128+128).
// B LDS layout: 16B chunk (brow, c8) stored at slot brow*8 + (c8 ^ (brow&7)).
// glds requires lane-contiguous dest, so the swizzle is applied to the
// per-lane GLOBAL source address instead; fragment reads land 2-way (free).
__launch_bounds__(256)
__global__ void scores_gemm(const float* __restrict__ x,
                            const unsigned short* __restrict__ Wb,
                            const float* __restrict__ u,
                            const int* __restrict__ doc,
                            float* __restrict__ part) {
    __shared__ __align__(16) unsigned short As[2][8 * 16 * APAD];  // 2 x 18432 B
    __shared__ __align__(16) unsigned short Bs[2][128 * BK];       // 2 x 16384 B
    __shared__ float s_red[4][128];

    const int ft = blockIdx.x;          // ft fastest: 8 ft-blocks of a bag concurrent
    const int b  = blockIdx.y;
    const int start = doc[2 * b], end = doc[2 * b + 1];
    const int strip0 = start >> 4;
    const int ns = ((end + 15) >> 4) - strip0;     // 1..8 strips of 16 rows
    const int row0 = strip0 << 4;

    const int tid  = threadIdx.x;
    const int wave = tid >> 6;
    const int lane = tid & 63;
    const int quad = lane >> 4;
    const int l16  = lane & 15;
    const int arow = tid >> 4;          // 0..15: row within a 16-row strip
    const int acol = (tid & 15) << 2;   // 4-float column group

    const float* xbase = x + ((size_t)b * Ss + row0) * Ee;
    const unsigned short* wbase = Wb + (size_t)ft * 128 * Ee;

    f32x4 acc[8][2];
    #pragma unroll
    for (int i = 0; i < 8; ++i)
        #pragma unroll
        for (int j = 0; j < 2; ++j) acc[i][j] = (f32x4){0.f, 0.f, 0.f, 0.f};

    // ---- prologue: stage tile 0 into buffer 0 ----
    #pragma unroll
    for (int r = 0; r < 8; ++r) if (r < ns) {
        int row = (r << 4) | arow;
        float4 v = *reinterpret_cast<const float4*>(xbase + (size_t)row * Ee + acol);
        ushort4 o; o.x = f2bf(v.x); o.y = f2bf(v.y); o.z = f2bf(v.z); o.w = f2bf(v.w);
        *reinterpret_cast<ushort4*>(&As[0][row * APAD + acol]) = o;
    }
    #pragma unroll
    for (int r = 0; r < 4; ++r) {
        int chunk = (r << 8) | tid;
        int brow = chunk >> 3;
        int c8 = (chunk & 7) ^ (brow & 7);
        const unsigned short* src = wbase + (size_t)brow * Ee + (c8 << 3);
        __builtin_amdgcn_global_load_lds((const glb_u32*)src,
                                         (lds_u32*)&Bs[0][chunk << 3], 16, 0, 0);
    }
    __syncthreads();

    // ---- pipelined K loop: 16 iterations of BK=64 ----
    for (int t = 0; t < 16; ++t) {
        const int cb = t & 1, nb = cb ^ 1;
        const int k1 = (t + 1) << 6;

        float4 xa[8];
        if (t < 15) {
            // prefetch next A tile (fp32 -> regs), then issue next B glds
            #pragma unroll
            for (int r = 0; r < 8; ++r) if (r < ns) {
                int row = (r << 4) | arow;
                xa[r] = *reinterpret_cast<const float4*>(xbase + (size_t)row * Ee + k1 + acol);
            }
            #pragma unroll
            for (int r = 0; r < 4; ++r) {
                int chunk = (r << 8) | tid;
                int brow = chunk >> 3;
                int c8 = (chunk & 7) ^ (brow & 7);
                const unsigned short* src = wbase + (size_t)brow * Ee + k1 + (c8 << 3);
                __builtin_amdgcn_global_load_lds((const glb_u32*)src,
                                                 (lds_u32*)&Bs[nb][chunk << 3], 16, 0, 0);
            }
        }

        // MFMA on current buffers
        #pragma unroll
        for (int kk = 0; kk < BK; kk += 32) {
            const int n0 = wave * 32 + l16;
            const int n1 = n0 + 16;
            const int c8k = (kk >> 3) + quad;
            bf16x8 bf0 = *reinterpret_cast<const bf16x8*>(
                &Bs[cb][((n0 << 3) | (c8k ^ (n0 & 7))) << 3]);
            bf16x8 bf1 = *reinterpret_cast<const bf16x8*>(
                &Bs[cb][((n1 << 3) | (c8k ^ (n1 & 7))) << 3]);
            #pragma unroll
            for (int st = 0; st < 8; ++st) {
                if (st < ns) {   // block-uniform branch
                    bf16x8 af = *reinterpret_cast<const bf16x8*>(
                        &As[cb][(st * 16 + l16) * APAD + kk + quad * 8]);
                    acc[st][0] = __builtin_amdgcn_mfma_f32_16x16x32_bf16(af, bf0, acc[st][0], 0, 0, 0);
                    acc[st][1] = __builtin_amdgcn_mfma_f32_16x16x32_bf16(af, bf1, acc[st][1], 0, 0, 0);
                }
            }
        }

        if (t < 15) {
            // convert prefetched A and store into next buffer
            #pragma unroll
            for (int r = 0; r < 8; ++r) if (r < ns) {
                int row = (r << 4) | arow;
                ushort4 o;
                o.x = f2bf(xa[r].x); o.y = f2bf(xa[r].y);
                o.z = f2bf(xa[r].z); o.w = f2bf(xa[r].w);
                *reinterpret_cast<ushort4*>(&As[nb][row * APAD + acol]) = o;
            }
        }
        __syncthreads();
    }

    // ---- epilogue: tanh, *u, reduce over the 128 f-columns ----
    // C/D layout (16x16x32): col = lane&15, row = quad*4 + reg
    const float u0 = u[ft * 128 + wave * 32 + l16];
    const float u1 = u[ft * 128 + wave * 32 + 16 + l16];
    #pragma unroll
    for (int st = 0; st < 8; ++st) {
        if (st < ns) {
            float p[4];
            #pragma unroll
            for (int r = 0; r < 4; ++r)
                p[r] = tanhf(acc[st][0][r]) * u0 + tanhf(acc[st][1][r]) * u1;
            #pragma unroll
            for (int off = 8; off >= 1; off >>= 1) {
                #pragma unroll
                for (int r = 0; r < 4; ++r)
                    p[r] += __shfl_xor(p[r], off, 16);
            }
            if (l16 == 0) {
                #pragma unroll
                for (int r = 0; r < 4; ++r)
                    s_red[wave][st * 16 + quad * 4 + r] = p[r];
            }
        }
    }
    __syncthreads();
    if (tid < (ns << 4)) {
        float v = s_red[0][tid] + s_red[1][tid] + s_red[2][tid] + s_red[3][tid];
        part[((size_t)b * 8 + ft) * 128 + row0 + tid] = v;
    }
}

// ---------------------------------------------------------------------------
// Kernel 3: fused masked softmax + weighted sum. Block = bag, 256 threads.
__global__ void out_fused(const float* __restrict__ x,
                          const float* __restrict__ part,
                          const int* __restrict__ doc,
                          float* __restrict__ out,
                          float* __restrict__ keep) {
    int b = blockIdx.x, t = threadIdx.x;
    int start = doc[2 * b], end = doc[2 * b + 1];
    __shared__ float a_s[Ss];
    __shared__ float red[2];

    bool m = false;
    float sc = -INFINITY;
    if (t < Ss) {
        m = (t >= start) && (t < end);
        if (m) {
            sc = 0.f;
            #pragma unroll
            for (int ftl = 0; ftl < 8; ++ftl)
                sc += part[((size_t)b * 8 + ftl) * Ss + t];
        }
    }
    float v = sc;
    #pragma unroll
    for (int off = 32; off >= 1; off >>= 1)
        v = fmaxf(v, __shfl_xor(v, off, 64));
    if ((t & 63) == 0 && t < Ss) red[t >> 6] = v;
    __syncthreads();
    float mx = fmaxf(red[0], red[1]);
    float e = (t < Ss && m) ? expf(sc - mx) : 0.f;
    __syncthreads();
    v = e;
    #pragma unroll
    for (int off = 32; off >= 1; off >>= 1)
        v += __shfl_xor(v, off, 64);
    if ((t & 63) == 0 && t < Ss) red[t >> 6] = v;
    __syncthreads();
    if (t < Ss) {
        float a = e / (red[0] + red[1]);
        a_s[t] = a;
        if (b == Bb - 1) keep[t] = a;
    }
    __syncthreads();

    const float4* xb = reinterpret_cast<const float4*>(x + (size_t)b * Ss * Ee);
    float4 accv = {0.f, 0.f, 0.f, 0.f};
    for (int s = start; s < end; ++s) {
        float a = a_s[s];
        float4 xv = xb[s * 256 + t];
        accv.x += a * xv.x; accv.y += a * xv.y;
        accv.z += a * xv.z; accv.w += a * xv.w;
    }
    reinterpret_cast<float4*>(out)[b * 256 + t] = accv;
}

// ---------------------------------------------------------------------------
extern "C" void kernel_launch(void* const* d_in, const int* in_sizes, int n_in,
                              void* d_out, int out_size, void* d_ws, size_t ws_size,
                              hipStream_t stream) {
    const float* x  = (const float*)d_in[0];   // [B,S,E] f32
    const float* W  = (const float*)d_in[1];   // [E,E]   f32
    const float* u  = (const float*)d_in[2];   // [1,E]   f32
    const int* doc  = (const int*)d_in[3];     // [B,2]   i32
    float* out = (float*)d_out;                // [B*E] out_concat ++ [S] keep

    unsigned short* Wb = (unsigned short*)d_ws;                          // 2 MB
    float* part = (float*)((char*)d_ws + (size_t)Ee * Ee * 2);           // 1 MB

    convW_kernel<<<1024, 256, 0, stream>>>(W, Wb);
    scores_gemm<<<dim3(8, Bb), 256, 0, stream>>>(x, Wb, u, doc, part);
    out_fused<<<Bb, 256, 0, stream>>>(x, part, doc, out, out + (size_t)Bb * Ee);
}

// Round 3
// 321.019 us; speedup vs baseline: 1.0671x; 1.0671x over previous
//
#include <hip/hip_runtime.h>
#include <math.h>

// Problem constants (from reference): B=256, S=128, E=1024
#define Bb 256
#define Ss 128
#define Ee 1024
#define BK 64
#define APAD 72   // fallback-path A pad

typedef __bf16 bf16x8 __attribute__((ext_vector_type(8)));
typedef float f32x4 __attribute__((ext_vector_type(4)));

typedef __attribute__((address_space(3))) unsigned int lds_u32;
typedef __attribute__((address_space(1))) unsigned int glb_u32;

static __device__ __forceinline__ unsigned short f2bf(float f) {
    unsigned int u = __float_as_uint(f);
    u += 0x7FFFu + ((u >> 16) & 1u);
    return (unsigned short)(u >> 16);
}

// ---------------------------------------------------------------------------
// Kernel 1: convert W [E,E] f32 -> bf16 (2 MB in ws).
__global__ void convW_kernel(const float* __restrict__ W, unsigned short* __restrict__ Wb) {
    int i = blockIdx.x * blockDim.x + threadIdx.x;
    float4 v = reinterpret_cast<const float4*>(W)[i];
    ushort4 o;
    o.x = f2bf(v.x); o.y = f2bf(v.y); o.z = f2bf(v.z); o.w = f2bf(v.w);
    reinterpret_cast<ushort4*>(Wb)[i] = o;
}

// ---------------------------------------------------------------------------
// Kernel 1b: convert covered strips of x [B,S,E] f32 -> xb bf16.
// Block (strip st, bag b); inactive strips exit immediately.
__global__ void xconv_kernel(const float* __restrict__ x,
                             const int* __restrict__ doc,
                             unsigned short* __restrict__ xb) {
    const int st = blockIdx.x, b = blockIdx.y;
    const int start = doc[2 * b], end = doc[2 * b + 1];
    const int strip0 = start >> 4;
    const int ns = ((end + 15) >> 4) - strip0;
    if (st < strip0 || st >= strip0 + ns) return;
    const int tid = threadIdx.x;
    const size_t base = ((size_t)b * Ss + (st << 4)) * Ee;
    #pragma unroll
    for (int r = 0; r < 16; ++r) {
        size_t idx = base + (size_t)r * Ee + (tid << 2);
        float4 v = *reinterpret_cast<const float4*>(x + idx);
        ushort4 o;
        o.x = f2bf(v.x); o.y = f2bf(v.y); o.z = f2bf(v.z); o.w = f2bf(v.w);
        *reinterpret_cast<ushort4*>(xb + idx) = o;
    }
}

// ---------------------------------------------------------------------------
// Kernel 2 (primary): fused scores GEMM, all-bf16, glds A+B, double-buffered,
// XOR-swizzled chunk layout for both operands (2-way bank alias = free).
// Chunk (row, c8) lives at slot row*8 + (c8 ^ (row&7)); the swizzle is applied
// to the per-lane GLOBAL source column (glds dest must be lane-contiguous).
__launch_bounds__(256)
__global__ void scores_gemm_xb(const unsigned short* __restrict__ xb,
                               const unsigned short* __restrict__ Wb,
                               const float* __restrict__ u,
                               const int* __restrict__ doc,
                               float* __restrict__ part) {
    __shared__ __align__(16) unsigned short As[2][128 * BK];   // 2 x 16 KB
    __shared__ __align__(16) unsigned short Bs[2][128 * BK];   // 2 x 16 KB
    __shared__ float s_red[4][128];

    const int b  = blockIdx.x;          // b fastest (L2 locality for W slices)
    const int ft = blockIdx.y;
    const int start = doc[2 * b], end = doc[2 * b + 1];
    const int strip0 = start >> 4;
    const int ns = ((end + 15) >> 4) - strip0;     // 1..8 strips of 16 rows
    const int row0 = strip0 << 4;
    const int na = ns << 7;                        // ns*128 A chunks

    const int tid  = threadIdx.x;
    const int wave = tid >> 6;
    const int lane = tid & 63;
    const int quad = lane >> 4;
    const int l16  = lane & 15;

    const unsigned short* abase = xb + ((size_t)b * Ss + row0) * Ee;
    const unsigned short* wbase = Wb + (size_t)ft * 128 * Ee;

    f32x4 acc[8][2];
    #pragma unroll
    for (int i = 0; i < 8; ++i)
        #pragma unroll
        for (int j = 0; j < 2; ++j) acc[i][j] = (f32x4){0.f, 0.f, 0.f, 0.f};

    auto stage = [&](int buf, int k0) {
        // A: ns*128 chunks of 16B (wave-uniform guard: na is a multiple of 128)
        #pragma unroll
        for (int r = 0; r < 4; ++r) {
            int chunk = (r << 8) | tid;
            if (chunk < na) {
                int arow = chunk >> 3;
                int c8 = (chunk & 7) ^ (arow & 7);
                __builtin_amdgcn_global_load_lds(
                    (const glb_u32*)(abase + (size_t)arow * Ee + k0 + (c8 << 3)),
                    (lds_u32*)&As[buf][chunk << 3], 16, 0, 0);
            }
        }
        // B: 1024 chunks of 16B
        #pragma unroll
        for (int r = 0; r < 4; ++r) {
            int chunk = (r << 8) | tid;
            int brow = chunk >> 3;
            int c8 = (chunk & 7) ^ (brow & 7);
            __builtin_amdgcn_global_load_lds(
                (const glb_u32*)(wbase + (size_t)brow * Ee + k0 + (c8 << 3)),
                (lds_u32*)&Bs[buf][chunk << 3], 16, 0, 0);
        }
    };

    stage(0, 0);
    __syncthreads();

    for (int t = 0; t < 16; ++t) {
        const int cb = t & 1, nb = cb ^ 1;
        if (t < 15) stage(nb, (t + 1) << 6);   // in flight during MFMA phase

        #pragma unroll
        for (int kk = 0; kk < BK; kk += 32) {
            const int n0 = wave * 32 + l16;
            const int n1 = n0 + 16;
            const int c8k = (kk >> 3) + quad;
            bf16x8 bf0 = *reinterpret_cast<const bf16x8*>(
                &Bs[cb][((n0 << 3) | (c8k ^ (n0 & 7))) << 3]);
            bf16x8 bf1 = *reinterpret_cast<const bf16x8*>(
                &Bs[cb][((n1 << 3) | (c8k ^ (n1 & 7))) << 3]);
            #pragma unroll
            for (int st = 0; st < 8; ++st) {
                if (st < ns) {   // block-uniform branch
                    const int ar = st * 16 + l16;
                    bf16x8 af = *reinterpret_cast<const bf16x8*>(
                        &As[cb][((ar << 3) | (c8k ^ (ar & 7))) << 3]);
                    acc[st][0] = __builtin_amdgcn_mfma_f32_16x16x32_bf16(af, bf0, acc[st][0], 0, 0, 0);
                    acc[st][1] = __builtin_amdgcn_mfma_f32_16x16x32_bf16(af, bf1, acc[st][1], 0, 0, 0);
                }
            }
        }
        __syncthreads();
    }

    // epilogue: tanh, *u, reduce over the 128 f-columns of this tile
    const float u0 = u[ft * 128 + wave * 32 + l16];
    const float u1 = u[ft * 128 + wave * 32 + 16 + l16];
    #pragma unroll
    for (int st = 0; st < 8; ++st) {
        if (st < ns) {
            float p[4];
            #pragma unroll
            for (int r = 0; r < 4; ++r)
                p[r] = tanhf(acc[st][0][r]) * u0 + tanhf(acc[st][1][r]) * u1;
            #pragma unroll
            for (int off = 8; off >= 1; off >>= 1)
                #pragma unroll
                for (int r = 0; r < 4; ++r)
                    p[r] += __shfl_xor(p[r], off, 16);
            if (l16 == 0)
                #pragma unroll
                for (int r = 0; r < 4; ++r)
                    s_red[wave][st * 16 + quad * 4 + r] = p[r];
        }
    }
    __syncthreads();
    if (tid < (ns << 4)) {
        float v = s_red[0][tid] + s_red[1][tid] + s_red[2][tid] + s_red[3][tid];
        part[((size_t)b * 8 + ft) * 128 + row0 + tid] = v;
    }
}

// ---------------------------------------------------------------------------
// Kernel 2 (fallback, small ws): R2 version with in-kernel A conversion.
__launch_bounds__(256)
__global__ void scores_gemm_fb(const float* __restrict__ x,
                               const unsigned short* __restrict__ Wb,
                               const float* __restrict__ u,
                               const int* __restrict__ doc,
                               float* __restrict__ part) {
    __shared__ __align__(16) unsigned short As[8 * 16 * APAD];
    __shared__ __align__(16) unsigned short Bs[128 * BK];
    __shared__ float s_red[4][128];

    const int b  = blockIdx.x;
    const int ft = blockIdx.y;
    const int start = doc[2 * b], end = doc[2 * b + 1];
    const int strip0 = start >> 4;
    const int ns = ((end + 15) >> 4) - strip0;
    const int row0 = strip0 << 4;

    const int tid  = threadIdx.x;
    const int wave = tid >> 6;
    const int lane = tid & 63;
    const int quad = lane >> 4;
    const int l16  = lane & 15;
    const int arow = tid >> 4;
    const int acol = (tid & 15) << 2;

    const float* xbase = x + ((size_t)b * Ss + row0) * Ee;
    const unsigned short* wbase = Wb + (size_t)ft * 128 * Ee;

    f32x4 acc[8][2];
    #pragma unroll
    for (int i = 0; i < 8; ++i)
        #pragma unroll
        for (int j = 0; j < 2; ++j) acc[i][j] = (f32x4){0.f, 0.f, 0.f, 0.f};

    for (int k0 = 0; k0 < Ee; k0 += BK) {
        #pragma unroll
        for (int r = 0; r < 8; ++r) if (r < ns) {
            int row = (r << 4) | arow;
            float4 v = *reinterpret_cast<const float4*>(xbase + (size_t)row * Ee + k0 + acol);
            ushort4 o; o.x = f2bf(v.x); o.y = f2bf(v.y); o.z = f2bf(v.z); o.w = f2bf(v.w);
            *reinterpret_cast<ushort4*>(&As[row * APAD + acol]) = o;
        }
        #pragma unroll
        for (int r = 0; r < 4; ++r) {
            int chunk = (r << 8) | tid;
            int brow = chunk >> 3;
            int c8 = (chunk & 7) ^ (brow & 7);
            __builtin_amdgcn_global_load_lds(
                (const glb_u32*)(wbase + (size_t)brow * Ee + k0 + (c8 << 3)),
                (lds_u32*)&Bs[chunk << 3], 16, 0, 0);
        }
        __syncthreads();
        #pragma unroll
        for (int kk = 0; kk < BK; kk += 32) {
            const int n0 = wave * 32 + l16;
            const int n1 = n0 + 16;
            const int c8k = (kk >> 3) + quad;
            bf16x8 bf0 = *reinterpret_cast<const bf16x8*>(
                &Bs[((n0 << 3) | (c8k ^ (n0 & 7))) << 3]);
            bf16x8 bf1 = *reinterpret_cast<const bf16x8*>(
                &Bs[((n1 << 3) | (c8k ^ (n1 & 7))) << 3]);
            #pragma unroll
            for (int st = 0; st < 8; ++st) {
                if (st < ns) {
                    bf16x8 af = *reinterpret_cast<const bf16x8*>(
                        &As[(st * 16 + l16) * APAD + kk + quad * 8]);
                    acc[st][0] = __builtin_amdgcn_mfma_f32_16x16x32_bf16(af, bf0, acc[st][0], 0, 0, 0);
                    acc[st][1] = __builtin_amdgcn_mfma_f32_16x16x32_bf16(af, bf1, acc[st][1], 0, 0, 0);
                }
            }
        }
        __syncthreads();
    }

    const float u0 = u[ft * 128 + wave * 32 + l16];
    const float u1 = u[ft * 128 + wave * 32 + 16 + l16];
    #pragma unroll
    for (int st = 0; st < 8; ++st) {
        if (st < ns) {
            float p[4];
            #pragma unroll
            for (int r = 0; r < 4; ++r)
                p[r] = tanhf(acc[st][0][r]) * u0 + tanhf(acc[st][1][r]) * u1;
            #pragma unroll
            for (int off = 8; off >= 1; off >>= 1)
                #pragma unroll
                for (int r = 0; r < 4; ++r)
                    p[r] += __shfl_xor(p[r], off, 16);
            if (l16 == 0)
                #pragma unroll
                for (int r = 0; r < 4; ++r)
                    s_red[wave][st * 16 + quad * 4 + r] = p[r];
        }
    }
    __syncthreads();
    if (tid < (ns << 4)) {
        float v = s_red[0][tid] + s_red[1][tid] + s_red[2][tid] + s_red[3][tid];
        part[((size_t)b * 8 + ft) * 128 + row0 + tid] = v;
    }
}

// ---------------------------------------------------------------------------
// Kernel 3: masked softmax per bag. Writes attn (ws) + keep (tail of out).
__global__ void softmax_kernel(const float* __restrict__ part,
                               const int* __restrict__ doc,
                               float* __restrict__ attn,
                               float* __restrict__ keep) {
    int b = blockIdx.x, s = threadIdx.x;
    int start = doc[2 * b], end = doc[2 * b + 1];
    bool m = (s >= start) && (s < end);
    float sc = -INFINITY;
    if (m) {
        sc = 0.f;
        #pragma unroll
        for (int ft = 0; ft < 8; ++ft)
            sc += part[((size_t)b * 8 + ft) * Ss + s];
    }
    __shared__ float red[2];
    float v = sc;
    #pragma unroll
    for (int off = 32; off >= 1; off >>= 1)
        v = fmaxf(v, __shfl_xor(v, off, 64));
    if ((s & 63) == 0) red[s >> 6] = v;
    __syncthreads();
    float mx = fmaxf(red[0], red[1]);
    __syncthreads();
    float e = m ? expf(sc - mx) : 0.f;
    v = e;
    #pragma unroll
    for (int off = 32; off >= 1; off >>= 1)
        v += __shfl_xor(v, off, 64);
    if ((s & 63) == 0) red[s >> 6] = v;
    __syncthreads();
    float a = e / (red[0] + red[1]);
    attn[b * Ss + s] = a;
    if (b == Bb - 1) keep[s] = a;
}

// ---------------------------------------------------------------------------
// Kernel 4: out[b,e] += sum over a 16-row s-chunk of attn*x. Grid (8, Bb).
// fp32 atomicAdd into memset-zeroed out; <=8 colliders per address.
__global__ void out_partial(const float* __restrict__ x,
                            const float* __restrict__ attn,
                            const int* __restrict__ doc,
                            float* __restrict__ out) {
    const int c = blockIdx.x, b = blockIdx.y, t = threadIdx.x;
    const int start = doc[2 * b], end = doc[2 * b + 1];
    const int slo = max(start, c << 4), shi = min(end, (c << 4) + 16);
    if (slo >= shi) return;                       // block-uniform
    __shared__ float a_s[16];
    if (t < 16) {
        int s = (c << 4) + t;
        a_s[t] = (s >= start && s < end) ? attn[b * Ss + s] : 0.f;
    }
    __syncthreads();
    const float4* xb4 = reinterpret_cast<const float4*>(x + (size_t)b * Ss * Ee);
    float4 accv = {0.f, 0.f, 0.f, 0.f};
    for (int s = slo; s < shi; ++s) {
        float a = a_s[s - (c << 4)];
        float4 xv = xb4[s * 256 + t];
        accv.x += a * xv.x; accv.y += a * xv.y;
        accv.z += a * xv.z; accv.w += a * xv.w;
    }
    float* o = out + (size_t)b * Ee + (t << 2);
    atomicAdd(o + 0, accv.x);
    atomicAdd(o + 1, accv.y);
    atomicAdd(o + 2, accv.z);
    atomicAdd(o + 3, accv.w);
}

// ---------------------------------------------------------------------------
extern "C" void kernel_launch(void* const* d_in, const int* in_sizes, int n_in,
                              void* d_out, int out_size, void* d_ws, size_t ws_size,
                              hipStream_t stream) {
    const float* x  = (const float*)d_in[0];   // [B,S,E] f32
    const float* W  = (const float*)d_in[1];   // [E,E]   f32
    const float* u  = (const float*)d_in[2];   // [1,E]   f32
    const int* doc  = (const int*)d_in[3];     // [B,2]   i32
    float* out = (float*)d_out;                // [B*E] out_concat ++ [S] keep

    const size_t szWb   = (size_t)Ee * Ee * 2;          // 2 MB
    const size_t szXb   = (size_t)Bb * Ss * Ee * 2;     // 64 MB
    const size_t szPart = (size_t)Bb * 8 * Ss * 4;      // 1 MB
    const size_t szAttn = (size_t)Bb * Ss * 4;          // 128 KB

    unsigned short* Wb = (unsigned short*)d_ws;
    const bool big_ws = ws_size >= szWb + szXb + szPart + szAttn;

    hipMemsetAsync(out, 0, (size_t)Bb * Ee * sizeof(float), stream);
    convW_kernel<<<1024, 256, 0, stream>>>(W, Wb);

    float* part;
    float* attn;
    if (big_ws) {
        unsigned short* xb = (unsigned short*)((char*)d_ws + szWb);
        part = (float*)((char*)d_ws + szWb + szXb);
        attn = (float*)((char*)d_ws + szWb + szXb + szPart);
        xconv_kernel<<<dim3(8, Bb), 256, 0, stream>>>(x, doc, xb);
        scores_gemm_xb<<<dim3(Bb, 8), 256, 0, stream>>>(xb, Wb, u, doc, part);
    } else {
        part = (float*)((char*)d_ws + szWb);
        attn = (float*)((char*)d_ws + szWb + szPart);
        scores_gemm_fb<<<dim3(Bb, 8), 256, 0, stream>>>(x, Wb, u, doc, part);
    }
    softmax_kernel<<<Bb, 128, 0, stream>>>(part, doc, attn, out + (size_t)Bb * Ee);
    out_partial<<<dim3(8, Bb), 256, 0, stream>>>(x, attn, doc, out);
}

// Round 4
// 280.457 us; speedup vs baseline: 1.2214x; 1.1446x over previous
//
#include <hip/hip_runtime.h>
#include <math.h>

// Problem constants (from reference): B=256, S=128, E=1024
#define Bb 256
#define Ss 128
#define Ee 1024
#define BK 64
#define APAD 72   // fallback-path A pad

typedef __bf16 bf16x8 __attribute__((ext_vector_type(8)));
typedef float f32x4 __attribute__((ext_vector_type(4)));

typedef __attribute__((address_space(3))) unsigned int lds_u32;
typedef __attribute__((address_space(1))) unsigned int glb_u32;

static __device__ __forceinline__ unsigned short f2bf(float f) {
    unsigned int u = __float_as_uint(f);
    u += 0x7FFFu + ((u >> 16) & 1u);
    return (unsigned short)(u >> 16);
}
static __device__ __forceinline__ float bf2f(unsigned short h) {
    return __uint_as_float((unsigned int)h << 16);
}

// ---------------------------------------------------------------------------
// Kernel 1: fused conversion. Grid (8, Bb+128).
//  by <  Bb : convert covered 16-row strip `st` of bag `by` (x f32 -> xb bf16)
//  by >= Bb : convert a 1024-float4 slice of W  (f32 -> bf16)
__global__ void conv_all(const float* __restrict__ x,
                         const float* __restrict__ W,
                         const int* __restrict__ doc,
                         unsigned short* __restrict__ xb,
                         unsigned short* __restrict__ Wb) {
    const int st = blockIdx.x, by = blockIdx.y, tid = threadIdx.x;
    if (by >= Bb) {
        int i = ((((by - Bb) << 3) | st) << 8) | tid;   // 1024 blocks x 256 float4
        float4 v = reinterpret_cast<const float4*>(W)[i];
        ushort4 o;
        o.x = f2bf(v.x); o.y = f2bf(v.y); o.z = f2bf(v.z); o.w = f2bf(v.w);
        reinterpret_cast<ushort4*>(Wb)[i] = o;
        return;
    }
    const int b = by;
    const int start = doc[2 * b], end = doc[2 * b + 1];
    const int strip0 = start >> 4;
    const int ns = ((end + 15) >> 4) - strip0;
    if (st < strip0 || st >= strip0 + ns) return;
    const size_t base = ((size_t)b * Ss + (st << 4)) * Ee;
    #pragma unroll
    for (int r = 0; r < 16; ++r) {
        size_t idx = base + (size_t)r * Ee + (tid << 2);
        float4 v = *reinterpret_cast<const float4*>(x + idx);
        ushort4 o;
        o.x = f2bf(v.x); o.y = f2bf(v.y); o.z = f2bf(v.z); o.w = f2bf(v.w);
        *reinterpret_cast<ushort4*>(xb + idx) = o;
    }
}

// Fallback W-only conversion (small ws path).
__global__ void convW_kernel(const float* __restrict__ W, unsigned short* __restrict__ Wb) {
    int i = blockIdx.x * blockDim.x + threadIdx.x;
    float4 v = reinterpret_cast<const float4*>(W)[i];
    ushort4 o;
    o.x = f2bf(v.x); o.y = f2bf(v.y); o.z = f2bf(v.z); o.w = f2bf(v.w);
    reinterpret_cast<ushort4*>(Wb)[i] = o;
}

// ---------------------------------------------------------------------------
// Kernel 2 (primary): fused scores GEMM. SINGLE-buffered (34 KB LDS -> 4
// blocks/CU), glds A+B, XOR-swizzled chunk layout (bank-conflict-free,
// verified R3: SQ_LDS_BANK_CONFLICT=0). Chunk (row,c8) lives at LDS slot
// row*8 + (c8 ^ (row&7)); swizzle applied to the global source column.
// part layout: part[(b*Ss + s)*8 + ft]  (contiguous ft for the softmax read).
__launch_bounds__(256, 4)
__global__ void scores_gemm_xb(const unsigned short* __restrict__ xb,
                               const unsigned short* __restrict__ Wb,
                               const float* __restrict__ u,
                               const int* __restrict__ doc,
                               float* __restrict__ part) {
    __shared__ __align__(16) unsigned short As[128 * BK];   // 16 KB
    __shared__ __align__(16) unsigned short Bs[128 * BK];   // 16 KB
    __shared__ float s_red[4][128];                         // 2 KB

    const int b  = blockIdx.x;          // b fastest: W slices stay L2-hot
    const int ft = blockIdx.y;
    const int start = doc[2 * b], end = doc[2 * b + 1];
    const int strip0 = start >> 4;
    const int ns = ((end + 15) >> 4) - strip0;     // 1..8 strips of 16 rows
    const int row0 = strip0 << 4;
    const int na = ns << 7;                        // ns*128 A chunks (wave-uniform guard)

    const int tid  = threadIdx.x;
    const int wave = tid >> 6;
    const int lane = tid & 63;
    const int quad = lane >> 4;
    const int l16  = lane & 15;

    const unsigned short* abase = xb + ((size_t)b * Ss + row0) * Ee;
    const unsigned short* wbase = Wb + (size_t)ft * 128 * Ee;

    f32x4 acc[8][2];
    #pragma unroll
    for (int i = 0; i < 8; ++i)
        #pragma unroll
        for (int j = 0; j < 2; ++j) acc[i][j] = (f32x4){0.f, 0.f, 0.f, 0.f};

    for (int t = 0; t < 16; ++t) {
        const int k0 = t << 6;
        // stage A: ns*128 chunks of 16B
        #pragma unroll
        for (int r = 0; r < 4; ++r) {
            int chunk = (r << 8) | tid;
            if (chunk < na) {
                int arow = chunk >> 3;
                int c8 = (chunk & 7) ^ (arow & 7);
                __builtin_amdgcn_global_load_lds(
                    (const glb_u32*)(abase + (size_t)arow * Ee + k0 + (c8 << 3)),
                    (lds_u32*)&As[chunk << 3], 16, 0, 0);
            }
        }
        // stage B: 1024 chunks of 16B
        #pragma unroll
        for (int r = 0; r < 4; ++r) {
            int chunk = (r << 8) | tid;
            int brow = chunk >> 3;
            int c8 = (chunk & 7) ^ (brow & 7);
            __builtin_amdgcn_global_load_lds(
                (const glb_u32*)(wbase + (size_t)brow * Ee + k0 + (c8 << 3)),
                (lds_u32*)&Bs[chunk << 3], 16, 0, 0);
        }
        __syncthreads();

        #pragma unroll
        for (int kk = 0; kk < BK; kk += 32) {
            const int n0 = wave * 32 + l16;
            const int n1 = n0 + 16;
            const int c8k = (kk >> 3) + quad;
            bf16x8 bf0 = *reinterpret_cast<const bf16x8*>(
                &Bs[((n0 << 3) | (c8k ^ (n0 & 7))) << 3]);
            bf16x8 bf1 = *reinterpret_cast<const bf16x8*>(
                &Bs[((n1 << 3) | (c8k ^ (n1 & 7))) << 3]);
            #pragma unroll
            for (int st = 0; st < 8; ++st) {
                if (st < ns) {   // block-uniform branch
                    const int ar = st * 16 + l16;
                    bf16x8 af = *reinterpret_cast<const bf16x8*>(
                        &As[((ar << 3) | (c8k ^ (ar & 7))) << 3]);
                    acc[st][0] = __builtin_amdgcn_mfma_f32_16x16x32_bf16(af, bf0, acc[st][0], 0, 0, 0);
                    acc[st][1] = __builtin_amdgcn_mfma_f32_16x16x32_bf16(af, bf1, acc[st][1], 0, 0, 0);
                }
            }
        }
        __syncthreads();   // MFMA reads done before next stage overwrites
    }

    // epilogue: tanh, *u, reduce over this tile's 128 f-columns
    const float u0 = u[ft * 128 + wave * 32 + l16];
    const float u1 = u[ft * 128 + wave * 32 + 16 + l16];
    #pragma unroll
    for (int st = 0; st < 8; ++st) {
        if (st < ns) {
            float p[4];
            #pragma unroll
            for (int r = 0; r < 4; ++r)
                p[r] = tanhf(acc[st][0][r]) * u0 + tanhf(acc[st][1][r]) * u1;
            #pragma unroll
            for (int off = 8; off >= 1; off >>= 1)
                #pragma unroll
                for (int r = 0; r < 4; ++r)
                    p[r] += __shfl_xor(p[r], off, 16);
            if (l16 == 0)
                #pragma unroll
                for (int r = 0; r < 4; ++r)
                    s_red[wave][st * 16 + quad * 4 + r] = p[r];
        }
    }
    __syncthreads();
    if (tid < (ns << 4)) {
        float v = s_red[0][tid] + s_red[1][tid] + s_red[2][tid] + s_red[3][tid];
        part[((size_t)(b * Ss + row0 + tid) << 3) | ft] = v;
    }
}

// ---------------------------------------------------------------------------
// Kernel 2 (fallback, small ws): in-kernel A conversion from fp32 x.
__launch_bounds__(256)
__global__ void scores_gemm_fb(const float* __restrict__ x,
                               const unsigned short* __restrict__ Wb,
                               const float* __restrict__ u,
                               const int* __restrict__ doc,
                               float* __restrict__ part) {
    __shared__ __align__(16) unsigned short As[8 * 16 * APAD];
    __shared__ __align__(16) unsigned short Bs[128 * BK];
    __shared__ float s_red[4][128];

    const int b  = blockIdx.x;
    const int ft = blockIdx.y;
    const int start = doc[2 * b], end = doc[2 * b + 1];
    const int strip0 = start >> 4;
    const int ns = ((end + 15) >> 4) - strip0;
    const int row0 = strip0 << 4;

    const int tid  = threadIdx.x;
    const int wave = tid >> 6;
    const int lane = tid & 63;
    const int quad = lane >> 4;
    const int l16  = lane & 15;
    const int arow = tid >> 4;
    const int acol = (tid & 15) << 2;

    const float* xbase = x + ((size_t)b * Ss + row0) * Ee;
    const unsigned short* wbase = Wb + (size_t)ft * 128 * Ee;

    f32x4 acc[8][2];
    #pragma unroll
    for (int i = 0; i < 8; ++i)
        #pragma unroll
        for (int j = 0; j < 2; ++j) acc[i][j] = (f32x4){0.f, 0.f, 0.f, 0.f};

    for (int k0 = 0; k0 < Ee; k0 += BK) {
        #pragma unroll
        for (int r = 0; r < 8; ++r) if (r < ns) {
            int row = (r << 4) | arow;
            float4 v = *reinterpret_cast<const float4*>(xbase + (size_t)row * Ee + k0 + acol);
            ushort4 o; o.x = f2bf(v.x); o.y = f2bf(v.y); o.z = f2bf(v.z); o.w = f2bf(v.w);
            *reinterpret_cast<ushort4*>(&As[row * APAD + acol]) = o;
        }
        #pragma unroll
        for (int r = 0; r < 4; ++r) {
            int chunk = (r << 8) | tid;
            int brow = chunk >> 3;
            int c8 = (chunk & 7) ^ (brow & 7);
            __builtin_amdgcn_global_load_lds(
                (const glb_u32*)(wbase + (size_t)brow * Ee + k0 + (c8 << 3)),
                (lds_u32*)&Bs[chunk << 3], 16, 0, 0);
        }
        __syncthreads();
        #pragma unroll
        for (int kk = 0; kk < BK; kk += 32) {
            const int n0 = wave * 32 + l16;
            const int n1 = n0 + 16;
            const int c8k = (kk >> 3) + quad;
            bf16x8 bf0 = *reinterpret_cast<const bf16x8*>(
                &Bs[((n0 << 3) | (c8k ^ (n0 & 7))) << 3]);
            bf16x8 bf1 = *reinterpret_cast<const bf16x8*>(
                &Bs[((n1 << 3) | (c8k ^ (n1 & 7))) << 3]);
            #pragma unroll
            for (int st = 0; st < 8; ++st) {
                if (st < ns) {
                    bf16x8 af = *reinterpret_cast<const bf16x8*>(
                        &As[(st * 16 + l16) * APAD + kk + quad * 8]);
                    acc[st][0] = __builtin_amdgcn_mfma_f32_16x16x32_bf16(af, bf0, acc[st][0], 0, 0, 0);
                    acc[st][1] = __builtin_amdgcn_mfma_f32_16x16x32_bf16(af, bf1, acc[st][1], 0, 0, 0);
                }
            }
        }
        __syncthreads();
    }

    const float u0 = u[ft * 128 + wave * 32 + l16];
    const float u1 = u[ft * 128 + wave * 32 + 16 + l16];
    #pragma unroll
    for (int st = 0; st < 8; ++st) {
        if (st < ns) {
            float p[4];
            #pragma unroll
            for (int r = 0; r < 4; ++r)
                p[r] = tanhf(acc[st][0][r]) * u0 + tanhf(acc[st][1][r]) * u1;
            #pragma unroll
            for (int off = 8; off >= 1; off >>= 1)
                #pragma unroll
                for (int r = 0; r < 4; ++r)
                    p[r] += __shfl_xor(p[r], off, 16);
            if (l16 == 0)
                #pragma unroll
                for (int r = 0; r < 4; ++r)
                    s_red[wave][st * 16 + quad * 4 + r] = p[r];
        }
    }
    __syncthreads();
    if (tid < (ns << 4)) {
        float v = s_red[0][tid] + s_red[1][tid] + s_red[2][tid] + s_red[3][tid];
        part[((size_t)(b * Ss + row0 + tid) << 3) | ft] = v;
    }
}

// ---------------------------------------------------------------------------
// Kernel 3: fused softmax + weighted sum. Grid (8 s-chunks, Bb). 256 threads.
// Each block recomputes the bag softmax from part (1 KB), then accumulates
// its 16-row chunk of sum_s attn*x into out via fp32 atomics (out pre-zeroed).
// If xb != nullptr read bf16 xb, else fp32 x.
__global__ void out_fused(const unsigned short* __restrict__ xb,
                          const float* __restrict__ x,
                          const float* __restrict__ part,
                          const int* __restrict__ doc,
                          float* __restrict__ out,
                          float* __restrict__ keep) {
    const int c = blockIdx.x, b = blockIdx.y, t = threadIdx.x;
    const int start = doc[2 * b], end = doc[2 * b + 1];
    __shared__ float a_s[Ss];
    __shared__ float red[2];

    bool m = false;
    float sc = -INFINITY;
    if (t < Ss) {
        m = (t >= start) && (t < end);
        if (m) {
            const float4* p = reinterpret_cast<const float4*>(part + ((size_t)(b * Ss + t) << 3));
            float4 p0 = p[0], p1 = p[1];
            sc = ((p0.x + p0.y) + (p0.z + p0.w)) + ((p1.x + p1.y) + (p1.z + p1.w));
        }
    }
    float v = sc;
    #pragma unroll
    for (int off = 32; off >= 1; off >>= 1)
        v = fmaxf(v, __shfl_xor(v, off, 64));
    if (t < Ss && (t & 63) == 0) red[t >> 6] = v;
    __syncthreads();
    const float mx = fmaxf(red[0], red[1]);
    __syncthreads();
    const float e = m ? __expf(sc - mx) : 0.f;
    v = e;
    #pragma unroll
    for (int off = 32; off >= 1; off >>= 1)
        v += __shfl_xor(v, off, 64);
    if (t < Ss && (t & 63) == 0) red[t >> 6] = v;
    __syncthreads();
    if (t < Ss) a_s[t] = e / (red[0] + red[1]);
    __syncthreads();
    if (b == Bb - 1 && c == 0 && t < Ss) keep[t] = a_s[t];

    const int slo = max(start, c << 4), shi = min(end, (c << 4) + 16);
    if (slo >= shi) return;                 // block-uniform

    float4 accv = {0.f, 0.f, 0.f, 0.f};
    if (xb) {
        const unsigned short* xr = xb + (size_t)b * Ss * Ee;
        for (int s = slo; s < shi; ++s) {
            float a = a_s[s];
            ushort4 q = *reinterpret_cast<const ushort4*>(xr + (size_t)s * Ee + (t << 2));
            accv.x += a * bf2f(q.x); accv.y += a * bf2f(q.y);
            accv.z += a * bf2f(q.z); accv.w += a * bf2f(q.w);
        }
    } else {
        const float4* xr = reinterpret_cast<const float4*>(x + (size_t)b * Ss * Ee);
        for (int s = slo; s < shi; ++s) {
            float a = a_s[s];
            float4 q = xr[s * 256 + t];
            accv.x += a * q.x; accv.y += a * q.y;
            accv.z += a * q.z; accv.w += a * q.w;
        }
    }
    float* o = out + (size_t)b * Ee + (t << 2);
    atomicAdd(o + 0, accv.x);
    atomicAdd(o + 1, accv.y);
    atomicAdd(o + 2, accv.z);
    atomicAdd(o + 3, accv.w);
}

// ---------------------------------------------------------------------------
extern "C" void kernel_launch(void* const* d_in, const int* in_sizes, int n_in,
                              void* d_out, int out_size, void* d_ws, size_t ws_size,
                              hipStream_t stream) {
    const float* x  = (const float*)d_in[0];   // [B,S,E] f32
    const float* W  = (const float*)d_in[1];   // [E,E]   f32
    const float* u  = (const float*)d_in[2];   // [1,E]   f32
    const int* doc  = (const int*)d_in[3];     // [B,2]   i32
    float* out = (float*)d_out;                // [B*E] out_concat ++ [S] keep

    const size_t szWb   = (size_t)Ee * Ee * 2;          // 2 MB
    const size_t szXb   = (size_t)Bb * Ss * Ee * 2;     // 64 MB
    const size_t szPart = (size_t)Bb * Ss * 8 * 4;      // 1 MB

    unsigned short* Wb = (unsigned short*)d_ws;
    const bool big_ws = ws_size >= szWb + szXb + szPart;

    hipMemsetAsync(out, 0, (size_t)Bb * Ee * sizeof(float), stream);

    if (big_ws) {
        unsigned short* xbuf = (unsigned short*)((char*)d_ws + szWb);
        float* part = (float*)((char*)d_ws + szWb + szXb);
        conv_all<<<dim3(8, Bb + 128), 256, 0, stream>>>(x, W, doc, xbuf, Wb);
        scores_gemm_xb<<<dim3(Bb, 8), 256, 0, stream>>>(xbuf, Wb, u, doc, part);
        out_fused<<<dim3(8, Bb), 256, 0, stream>>>(xbuf, x, part, doc, out, out + (size_t)Bb * Ee);
    } else {
        float* part = (float*)((char*)d_ws + szWb);
        convW_kernel<<<1024, 256, 0, stream>>>(W, Wb);
        scores_gemm_fb<<<dim3(Bb, 8), 256, 0, stream>>>(x, Wb, u, doc, part);
        out_fused<<<dim3(8, Bb), 256, 0, stream>>>(nullptr, x, part, doc, out, out + (size_t)Bb * Ee);
    }
}

// Round 5
// 280.129 us; speedup vs baseline: 1.2229x; 1.0012x over previous
//
#include <hip/hip_runtime.h>
#include <math.h>

// Problem constants (from reference): B=256, S=128, E=1024
#define Bb 256
#define Ss 128
#define Ee 1024
#define BK 64
#define APAD 72   // fallback-path A pad

typedef __bf16 bf16x8 __attribute__((ext_vector_type(8)));
typedef float f32x4 __attribute__((ext_vector_type(4)));

typedef __attribute__((address_space(3))) unsigned int lds_u32;
typedef __attribute__((address_space(1))) unsigned int glb_u32;

static __device__ __forceinline__ unsigned short f2bf(float f) {
    unsigned int u = __float_as_uint(f);
    u += 0x7FFFu + ((u >> 16) & 1u);
    return (unsigned short)(u >> 16);
}
static __device__ __forceinline__ float bf2f(unsigned short h) {
    return __uint_as_float((unsigned int)h << 16);
}

// ---------------------------------------------------------------------------
// Kernel 1: fused conversion. Grid (8, Bb+128).
//  by <  Bb : convert covered 16-row strip `st` of bag `by` (x f32 -> xb bf16)
//  by >= Bb : convert a 1024-float4 slice of W  (f32 -> bf16)
__global__ void conv_all(const float* __restrict__ x,
                         const float* __restrict__ W,
                         const int* __restrict__ doc,
                         unsigned short* __restrict__ xb,
                         unsigned short* __restrict__ Wb) {
    const int st = blockIdx.x, by = blockIdx.y, tid = threadIdx.x;
    if (by >= Bb) {
        int i = ((((by - Bb) << 3) | st) << 8) | tid;   // 1024 blocks x 256 float4
        float4 v = reinterpret_cast<const float4*>(W)[i];
        ushort4 o;
        o.x = f2bf(v.x); o.y = f2bf(v.y); o.z = f2bf(v.z); o.w = f2bf(v.w);
        reinterpret_cast<ushort4*>(Wb)[i] = o;
        return;
    }
    const int b = by;
    const int start = doc[2 * b], end = doc[2 * b + 1];
    const int strip0 = start >> 4;
    const int ns = ((end + 15) >> 4) - strip0;
    if (st < strip0 || st >= strip0 + ns) return;
    const size_t base = ((size_t)b * Ss + (st << 4)) * Ee;
    #pragma unroll
    for (int r = 0; r < 16; ++r) {
        size_t idx = base + (size_t)r * Ee + (tid << 2);
        float4 v = *reinterpret_cast<const float4*>(x + idx);
        ushort4 o;
        o.x = f2bf(v.x); o.y = f2bf(v.y); o.z = f2bf(v.z); o.w = f2bf(v.w);
        *reinterpret_cast<ushort4*>(xb + idx) = o;
    }
}

// Fallback W-only conversion (small ws path).
__global__ void convW_kernel(const float* __restrict__ W, unsigned short* __restrict__ Wb) {
    int i = blockIdx.x * blockDim.x + threadIdx.x;
    float4 v = reinterpret_cast<const float4*>(W)[i];
    ushort4 o;
    o.x = f2bf(v.x); o.y = f2bf(v.y); o.z = f2bf(v.z); o.w = f2bf(v.w);
    reinterpret_cast<ushort4*>(Wb)[i] = o;
}

// ---------------------------------------------------------------------------
// Kernel 2 (primary): fused scores GEMM. M-split: each block covers <=4
// strips (grid z in {0,1}; second block exits for ns<=4). acc = 32 VGPRs,
// LDS = 25 KB -> 6 blocks/CU @ launch_bounds(256,6). Single-buffered glds
// A+B with XOR-swizzled chunk layout (SQ_LDS_BANK_CONFLICT=0, R3-verified).
// part layout: part[(b*Ss + s)*8 + ft].
__launch_bounds__(256, 6)
__global__ void scores_gemm_xb(const unsigned short* __restrict__ xb,
                               const unsigned short* __restrict__ Wb,
                               const float* __restrict__ u,
                               const int* __restrict__ doc,
                               float* __restrict__ part) {
    __shared__ __align__(16) unsigned short As[64 * BK];    // 8 KB
    __shared__ __align__(16) unsigned short Bs[128 * BK];   // 16 KB
    __shared__ float s_red[4][64];                          // 1 KB

    const int b  = blockIdx.x;          // b fastest: W slices stay L2-hot
    const int ft = blockIdx.y;
    const int mh = blockIdx.z;
    const int start = doc[2 * b], end = doc[2 * b + 1];
    const int strip0 = start >> 4;
    const int ns = ((end + 15) >> 4) - strip0;     // 1..8 strips of 16 rows
    const int ms0 = mh << 2;
    if (ms0 >= ns) return;                         // idle half-block
    const int nsl = min(ns - ms0, 4);              // 1..4 strips this block
    const int row0 = (strip0 + ms0) << 4;
    const int na = nsl << 7;                       // nsl*128 A chunks

    const int tid  = threadIdx.x;
    const int wave = tid >> 6;
    const int lane = tid & 63;
    const int quad = lane >> 4;
    const int l16  = lane & 15;

    const unsigned short* abase = xb + ((size_t)b * Ss + row0) * Ee;
    const unsigned short* wbase = Wb + (size_t)ft * 128 * Ee;

    f32x4 acc[4][2];
    #pragma unroll
    for (int i = 0; i < 4; ++i)
        #pragma unroll
        for (int j = 0; j < 2; ++j) acc[i][j] = (f32x4){0.f, 0.f, 0.f, 0.f};

    for (int t = 0; t < 16; ++t) {
        const int k0 = t << 6;
        // stage A: nsl*128 chunks of 16B (guard wave-uniform: na % 128 == 0)
        #pragma unroll
        for (int r = 0; r < 2; ++r) {
            int chunk = (r << 8) | tid;
            if (chunk < na) {
                int arow = chunk >> 3;
                int c8 = (chunk & 7) ^ (arow & 7);
                __builtin_amdgcn_global_load_lds(
                    (const glb_u32*)(abase + (size_t)arow * Ee + k0 + (c8 << 3)),
                    (lds_u32*)&As[chunk << 3], 16, 0, 0);
            }
        }
        // stage B: 1024 chunks of 16B
        #pragma unroll
        for (int r = 0; r < 4; ++r) {
            int chunk = (r << 8) | tid;
            int brow = chunk >> 3;
            int c8 = (chunk & 7) ^ (brow & 7);
            __builtin_amdgcn_global_load_lds(
                (const glb_u32*)(wbase + (size_t)brow * Ee + k0 + (c8 << 3)),
                (lds_u32*)&Bs[chunk << 3], 16, 0, 0);
        }
        __syncthreads();

        #pragma unroll
        for (int kk = 0; kk < BK; kk += 32) {
            const int n0 = wave * 32 + l16;
            const int n1 = n0 + 16;
            const int c8k = (kk >> 3) + quad;
            bf16x8 bf0 = *reinterpret_cast<const bf16x8*>(
                &Bs[((n0 << 3) | (c8k ^ (n0 & 7))) << 3]);
            bf16x8 bf1 = *reinterpret_cast<const bf16x8*>(
                &Bs[((n1 << 3) | (c8k ^ (n1 & 7))) << 3]);
            #pragma unroll
            for (int st = 0; st < 4; ++st) {
                if (st < nsl) {   // block-uniform branch
                    const int ar = st * 16 + l16;
                    bf16x8 af = *reinterpret_cast<const bf16x8*>(
                        &As[((ar << 3) | (c8k ^ (ar & 7))) << 3]);
                    acc[st][0] = __builtin_amdgcn_mfma_f32_16x16x32_bf16(af, bf0, acc[st][0], 0, 0, 0);
                    acc[st][1] = __builtin_amdgcn_mfma_f32_16x16x32_bf16(af, bf1, acc[st][1], 0, 0, 0);
                }
            }
        }
        __syncthreads();   // MFMA reads done before next stage overwrites
    }

    // epilogue: tanh, *u, reduce over this tile's 128 f-columns
    const float u0 = u[ft * 128 + wave * 32 + l16];
    const float u1 = u[ft * 128 + wave * 32 + 16 + l16];
    #pragma unroll
    for (int st = 0; st < 4; ++st) {
        if (st < nsl) {
            float p[4];
            #pragma unroll
            for (int r = 0; r < 4; ++r)
                p[r] = tanhf(acc[st][0][r]) * u0 + tanhf(acc[st][1][r]) * u1;
            #pragma unroll
            for (int off = 8; off >= 1; off >>= 1)
                #pragma unroll
                for (int r = 0; r < 4; ++r)
                    p[r] += __shfl_xor(p[r], off, 16);
            if (l16 == 0)
                #pragma unroll
                for (int r = 0; r < 4; ++r)
                    s_red[wave][st * 16 + quad * 4 + r] = p[r];
        }
    }
    __syncthreads();
    if (tid < (nsl << 4)) {
        float v = s_red[0][tid] + s_red[1][tid] + s_red[2][tid] + s_red[3][tid];
        part[((size_t)(b * Ss + row0 + tid) << 3) | ft] = v;
    }
}

// ---------------------------------------------------------------------------
// Kernel 2 (fallback, small ws): in-kernel A conversion from fp32 x.
__launch_bounds__(256)
__global__ void scores_gemm_fb(const float* __restrict__ x,
                               const unsigned short* __restrict__ Wb,
                               const float* __restrict__ u,
                               const int* __restrict__ doc,
                               float* __restrict__ part) {
    __shared__ __align__(16) unsigned short As[8 * 16 * APAD];
    __shared__ __align__(16) unsigned short Bs[128 * BK];
    __shared__ float s_red[4][128];

    const int b  = blockIdx.x;
    const int ft = blockIdx.y;
    const int start = doc[2 * b], end = doc[2 * b + 1];
    const int strip0 = start >> 4;
    const int ns = ((end + 15) >> 4) - strip0;
    const int row0 = strip0 << 4;

    const int tid  = threadIdx.x;
    const int wave = tid >> 6;
    const int lane = tid & 63;
    const int quad = lane >> 4;
    const int l16  = lane & 15;
    const int arow = tid >> 4;
    const int acol = (tid & 15) << 2;

    const float* xbase = x + ((size_t)b * Ss + row0) * Ee;
    const unsigned short* wbase = Wb + (size_t)ft * 128 * Ee;

    f32x4 acc[8][2];
    #pragma unroll
    for (int i = 0; i < 8; ++i)
        #pragma unroll
        for (int j = 0; j < 2; ++j) acc[i][j] = (f32x4){0.f, 0.f, 0.f, 0.f};

    for (int k0 = 0; k0 < Ee; k0 += BK) {
        #pragma unroll
        for (int r = 0; r < 8; ++r) if (r < ns) {
            int row = (r << 4) | arow;
            float4 v = *reinterpret_cast<const float4*>(xbase + (size_t)row * Ee + k0 + acol);
            ushort4 o; o.x = f2bf(v.x); o.y = f2bf(v.y); o.z = f2bf(v.z); o.w = f2bf(v.w);
            *reinterpret_cast<ushort4*>(&As[row * APAD + acol]) = o;
        }
        #pragma unroll
        for (int r = 0; r < 4; ++r) {
            int chunk = (r << 8) | tid;
            int brow = chunk >> 3;
            int c8 = (chunk & 7) ^ (brow & 7);
            __builtin_amdgcn_global_load_lds(
                (const glb_u32*)(wbase + (size_t)brow * Ee + k0 + (c8 << 3)),
                (lds_u32*)&Bs[chunk << 3], 16, 0, 0);
        }
        __syncthreads();
        #pragma unroll
        for (int kk = 0; kk < BK; kk += 32) {
            const int n0 = wave * 32 + l16;
            const int n1 = n0 + 16;
            const int c8k = (kk >> 3) + quad;
            bf16x8 bf0 = *reinterpret_cast<const bf16x8*>(
                &Bs[((n0 << 3) | (c8k ^ (n0 & 7))) << 3]);
            bf16x8 bf1 = *reinterpret_cast<const bf16x8*>(
                &Bs[((n1 << 3) | (c8k ^ (n1 & 7))) << 3]);
            #pragma unroll
            for (int st = 0; st < 8; ++st) {
                if (st < ns) {
                    bf16x8 af = *reinterpret_cast<const bf16x8*>(
                        &As[(st * 16 + l16) * APAD + kk + quad * 8]);
                    acc[st][0] = __builtin_amdgcn_mfma_f32_16x16x32_bf16(af, bf0, acc[st][0], 0, 0, 0);
                    acc[st][1] = __builtin_amdgcn_mfma_f32_16x16x32_bf16(af, bf1, acc[st][1], 0, 0, 0);
                }
            }
        }
        __syncthreads();
    }

    const float u0 = u[ft * 128 + wave * 32 + l16];
    const float u1 = u[ft * 128 + wave * 32 + 16 + l16];
    #pragma unroll
    for (int st = 0; st < 8; ++st) {
        if (st < ns) {
            float p[4];
            #pragma unroll
            for (int r = 0; r < 4; ++r)
                p[r] = tanhf(acc[st][0][r]) * u0 + tanhf(acc[st][1][r]) * u1;
            #pragma unroll
            for (int off = 8; off >= 1; off >>= 1)
                #pragma unroll
                for (int r = 0; r < 4; ++r)
                    p[r] += __shfl_xor(p[r], off, 16);
            if (l16 == 0)
                #pragma unroll
                for (int r = 0; r < 4; ++r)
                    s_red[wave][st * 16 + quad * 4 + r] = p[r];
        }
    }
    __syncthreads();
    if (tid < (ns << 4)) {
        float v = s_red[0][tid] + s_red[1][tid] + s_red[2][tid] + s_red[3][tid];
        part[((size_t)(b * Ss + row0 + tid) << 3) | ft] = v;
    }
}

// ---------------------------------------------------------------------------
// Kernel 3: fused softmax + weighted sum. Grid (4 s-chunks of 32, Bb).
// Each block recomputes the bag softmax from part (1 KB), then accumulates
// its 32-row chunk of sum_s attn*x into out via fp32 atomics (out pre-zeroed,
// <=4 colliders/address). If xb != nullptr read bf16 xb, else fp32 x.
__global__ void out_fused(const unsigned short* __restrict__ xb,
                          const float* __restrict__ x,
                          const float* __restrict__ part,
                          const int* __restrict__ doc,
                          float* __restrict__ out,
                          float* __restrict__ keep) {
    const int c = blockIdx.x, b = blockIdx.y, t = threadIdx.x;
    const int start = doc[2 * b], end = doc[2 * b + 1];
    __shared__ float a_s[Ss];
    __shared__ float red[2];

    bool m = false;
    float sc = -INFINITY;
    if (t < Ss) {
        m = (t >= start) && (t < end);
        if (m) {
            const float4* p = reinterpret_cast<const float4*>(part + ((size_t)(b * Ss + t) << 3));
            float4 p0 = p[0], p1 = p[1];
            sc = ((p0.x + p0.y) + (p0.z + p0.w)) + ((p1.x + p1.y) + (p1.z + p1.w));
        }
    }
    float v = sc;
    #pragma unroll
    for (int off = 32; off >= 1; off >>= 1)
        v = fmaxf(v, __shfl_xor(v, off, 64));
    if (t < Ss && (t & 63) == 0) red[t >> 6] = v;
    __syncthreads();
    const float mx = fmaxf(red[0], red[1]);
    __syncthreads();
    const float e = m ? __expf(sc - mx) : 0.f;
    v = e;
    #pragma unroll
    for (int off = 32; off >= 1; off >>= 1)
        v += __shfl_xor(v, off, 64);
    if (t < Ss && (t & 63) == 0) red[t >> 6] = v;
    __syncthreads();
    if (t < Ss) a_s[t] = e / (red[0] + red[1]);
    __syncthreads();
    if (b == Bb - 1 && c == 0 && t < Ss) keep[t] = a_s[t];

    const int slo = max(start, c << 5), shi = min(end, (c << 5) + 32);
    if (slo >= shi) return;                 // block-uniform

    float4 accv = {0.f, 0.f, 0.f, 0.f};
    if (xb) {
        const unsigned short* xr = xb + (size_t)b * Ss * Ee;
        for (int s = slo; s < shi; ++s) {
            float a = a_s[s];
            ushort4 q = *reinterpret_cast<const ushort4*>(xr + (size_t)s * Ee + (t << 2));
            accv.x += a * bf2f(q.x); accv.y += a * bf2f(q.y);
            accv.z += a * bf2f(q.z); accv.w += a * bf2f(q.w);
        }
    } else {
        const float4* xr = reinterpret_cast<const float4*>(x + (size_t)b * Ss * Ee);
        for (int s = slo; s < shi; ++s) {
            float a = a_s[s];
            float4 q = xr[s * 256 + t];
            accv.x += a * q.x; accv.y += a * q.y;
            accv.z += a * q.z; accv.w += a * q.w;
        }
    }
    float* o = out + (size_t)b * Ee + (t << 2);
    atomicAdd(o + 0, accv.x);
    atomicAdd(o + 1, accv.y);
    atomicAdd(o + 2, accv.z);
    atomicAdd(o + 3, accv.w);
}

// ---------------------------------------------------------------------------
extern "C" void kernel_launch(void* const* d_in, const int* in_sizes, int n_in,
                              void* d_out, int out_size, void* d_ws, size_t ws_size,
                              hipStream_t stream) {
    const float* x  = (const float*)d_in[0];   // [B,S,E] f32
    const float* W  = (const float*)d_in[1];   // [E,E]   f32
    const float* u  = (const float*)d_in[2];   // [1,E]   f32
    const int* doc  = (const int*)d_in[3];     // [B,2]   i32
    float* out = (float*)d_out;                // [B*E] out_concat ++ [S] keep

    const size_t szWb   = (size_t)Ee * Ee * 2;          // 2 MB
    const size_t szXb   = (size_t)Bb * Ss * Ee * 2;     // 64 MB
    const size_t szPart = (size_t)Bb * Ss * 8 * 4;      // 1 MB

    unsigned short* Wb = (unsigned short*)d_ws;
    const bool big_ws = ws_size >= szWb + szXb + szPart;

    hipMemsetAsync(out, 0, (size_t)Bb * Ee * sizeof(float), stream);

    if (big_ws) {
        unsigned short* xbuf = (unsigned short*)((char*)d_ws + szWb);
        float* part = (float*)((char*)d_ws + szWb + szXb);
        conv_all<<<dim3(8, Bb + 128), 256, 0, stream>>>(x, W, doc, xbuf, Wb);
        scores_gemm_xb<<<dim3(Bb, 8, 2), 256, 0, stream>>>(xbuf, Wb, u, doc, part);
        out_fused<<<dim3(4, Bb), 256, 0, stream>>>(xbuf, x, part, doc, out, out + (size_t)Bb * Ee);
    } else {
        float* part = (float*)((char*)d_ws + szWb);
        convW_kernel<<<1024, 256, 0, stream>>>(W, Wb);
        scores_gemm_fb<<<dim3(Bb, 8), 256, 0, stream>>>(x, Wb, u, doc, part);
        out_fused<<<dim3(4, Bb), 256, 0, stream>>>(nullptr, x, part, doc, out, out + (size_t)Bb * Ee);
    }
}

// Round 6
// 261.389 us; speedup vs baseline: 1.3105x; 1.0717x over previous
//
#include <hip/hip_runtime.h>
#include <math.h>

// Problem constants (from reference): B=256, S=128, E=1024
#define Bb 256
#define Ss 128
#define Ee 1024
#define BK 64
#define APAD 72    // fallback-path A pad
#define NMAX 2048  // max strips (256 bags x 8)

typedef __bf16 bf16x8 __attribute__((ext_vector_type(8)));
typedef float f32x4 __attribute__((ext_vector_type(4)));

typedef __attribute__((address_space(3))) unsigned int lds_u32;
typedef __attribute__((address_space(1))) unsigned int glb_u32;

static __device__ __forceinline__ unsigned short f2bf(float f) {
    unsigned int u = __float_as_uint(f);
    u += 0x7FFFu + ((u >> 16) & 1u);
    return (unsigned short)(u >> 16);
}
static __device__ __forceinline__ float bf2f(unsigned short h) {
    return __uint_as_float((unsigned int)h << 16);
}

// ---------------------------------------------------------------------------
// Kernel 0: build the global strip worklist. One block, 256 threads.
// list[i] = b*Ss + row0 for each covered 16-row strip, bag-major; pad -1.
__global__ void build_list(const int* __restrict__ doc, int* __restrict__ list) {
    __shared__ int sc[256];
    const int b = threadIdx.x;
    const int start = doc[2 * b], end = doc[2 * b + 1];
    const int s0 = start >> 4;
    const int ns = ((end + 15) >> 4) - s0;
    sc[b] = ns;
    __syncthreads();
    // Hillis-Steele inclusive scan over 256
    for (int d = 1; d < 256; d <<= 1) {
        int v = sc[b];
        int add = (b >= d) ? sc[b - d] : 0;
        __syncthreads();
        sc[b] = v + add;
        __syncthreads();
    }
    const int total = sc[255];
    const int off = sc[b] - ns;   // exclusive prefix
    for (int i = 0; i < ns; ++i)
        list[off + i] = b * Ss + ((s0 + i) << 4);
    for (int i = total + b; i < NMAX; i += 256)
        list[i] = -1;
}

// ---------------------------------------------------------------------------
// Kernel 1: fused conversion. Grid (8, Bb+128).
//  by <  Bb : convert covered 16-row strip `st` of bag `by` (x f32 -> xb bf16)
//  by >= Bb : convert a 1024-float4 slice of W  (f32 -> bf16)
__global__ void conv_all(const float* __restrict__ x,
                         const float* __restrict__ W,
                         const int* __restrict__ doc,
                         unsigned short* __restrict__ xb,
                         unsigned short* __restrict__ Wb) {
    const int st = blockIdx.x, by = blockIdx.y, tid = threadIdx.x;
    if (by >= Bb) {
        int i = ((((by - Bb) << 3) | st) << 8) | tid;   // 1024 blocks x 256 float4
        float4 v = reinterpret_cast<const float4*>(W)[i];
        ushort4 o;
        o.x = f2bf(v.x); o.y = f2bf(v.y); o.z = f2bf(v.z); o.w = f2bf(v.w);
        reinterpret_cast<ushort4*>(Wb)[i] = o;
        return;
    }
    const int b = by;
    const int start = doc[2 * b], end = doc[2 * b + 1];
    const int strip0 = start >> 4;
    const int ns = ((end + 15) >> 4) - strip0;
    if (st < strip0 || st >= strip0 + ns) return;
    const size_t base = ((size_t)b * Ss + (st << 4)) * Ee;
    #pragma unroll
    for (int r = 0; r < 16; ++r) {
        size_t idx = base + (size_t)r * Ee + (tid << 2);
        float4 v = *reinterpret_cast<const float4*>(x + idx);
        ushort4 o;
        o.x = f2bf(v.x); o.y = f2bf(v.y); o.z = f2bf(v.z); o.w = f2bf(v.w);
        *reinterpret_cast<ushort4*>(xb + idx) = o;
    }
}

// Fallback W-only conversion (small ws path).
__global__ void convW_kernel(const float* __restrict__ W, unsigned short* __restrict__ Wb) {
    int i = blockIdx.x * blockDim.x + threadIdx.x;
    float4 v = reinterpret_cast<const float4*>(W)[i];
    ushort4 o;
    o.x = f2bf(v.x); o.y = f2bf(v.y); o.z = f2bf(v.z); o.w = f2bf(v.w);
    reinterpret_cast<ushort4*>(Wb)[i] = o;
}

// ---------------------------------------------------------------------------
// Kernel 2 (primary): compacted-strip scores GEMM. Block (mb, ft) takes 4
// strips (possibly from different bags) from the worklist -> uniform full
// density: 16 MFMAs/wave/iter in every active block. LDS 25 KB, acc 32
// VGPRs -> 6 blocks/CU. glds A+B, XOR-swizzled chunks (conflict-free, R3).
// part layout: part[(b*Ss + s)*8 + ft].
__launch_bounds__(256, 6)
__global__ void scores_gemm_xb(const unsigned short* __restrict__ xb,
                               const unsigned short* __restrict__ Wb,
                               const float* __restrict__ u,
                               const int* __restrict__ list,
                               float* __restrict__ part) {
    __shared__ __align__(16) unsigned short As[64 * BK];    // 8 KB
    __shared__ __align__(16) unsigned short Bs[128 * BK];   // 16 KB
    __shared__ float s_red[4][64];                          // 1 KB

    const int mb = blockIdx.x;          // mb fastest: same W slice chip-wide
    const int ft = blockIdx.y;

    int e0 = list[mb << 2];
    if (e0 < 0) return;                 // fully-padded block
    int e[4];
    bool val[4];
    e[0] = e0; val[0] = true;
    #pragma unroll
    for (int j = 1; j < 4; ++j) {
        int v = list[(mb << 2) | j];
        val[j] = v >= 0;
        e[j] = val[j] ? v : e0;         // clamp padding to a valid strip
    }

    const int tid  = threadIdx.x;
    const int wave = tid >> 6;
    const int lane = tid & 63;
    const int quad = lane >> 4;
    const int l16  = lane & 15;

    const unsigned short* wbase = Wb + (size_t)ft * 128 * Ee;

    f32x4 acc[4][2];
    #pragma unroll
    for (int i = 0; i < 4; ++i)
        #pragma unroll
        for (int j = 0; j < 2; ++j) acc[i][j] = (f32x4){0.f, 0.f, 0.f, 0.f};

    for (int t = 0; t < 16; ++t) {
        const int k0 = t << 6;
        // stage A: 512 chunks of 16B (4 strips x 16 rows x 8 c8-groups)
        #pragma unroll
        for (int r = 0; r < 2; ++r) {
            int chunk = (r << 8) | tid;
            int arow = chunk >> 3;            // 0..63
            int strip = arow >> 4;
            int rowin = arow & 15;
            int c8 = (chunk & 7) ^ (arow & 7);
            __builtin_amdgcn_global_load_lds(
                (const glb_u32*)(xb + ((size_t)e[strip] + rowin) * Ee + k0 + (c8 << 3)),
                (lds_u32*)&As[chunk << 3], 16, 0, 0);
        }
        // stage B: 1024 chunks of 16B
        #pragma unroll
        for (int r = 0; r < 4; ++r) {
            int chunk = (r << 8) | tid;
            int brow = chunk >> 3;
            int c8 = (chunk & 7) ^ (brow & 7);
            __builtin_amdgcn_global_load_lds(
                (const glb_u32*)(wbase + (size_t)brow * Ee + k0 + (c8 << 3)),
                (lds_u32*)&Bs[chunk << 3], 16, 0, 0);
        }
        __syncthreads();

        #pragma unroll
        for (int kk = 0; kk < BK; kk += 32) {
            const int n0 = wave * 32 + l16;
            const int n1 = n0 + 16;
            const int c8k = (kk >> 3) + quad;
            bf16x8 bf0 = *reinterpret_cast<const bf16x8*>(
                &Bs[((n0 << 3) | (c8k ^ (n0 & 7))) << 3]);
            bf16x8 bf1 = *reinterpret_cast<const bf16x8*>(
                &Bs[((n1 << 3) | (c8k ^ (n1 & 7))) << 3]);
            #pragma unroll
            for (int st = 0; st < 4; ++st) {
                const int ar = st * 16 + l16;
                bf16x8 af = *reinterpret_cast<const bf16x8*>(
                    &As[((ar << 3) | (c8k ^ (ar & 7))) << 3]);
                acc[st][0] = __builtin_amdgcn_mfma_f32_16x16x32_bf16(af, bf0, acc[st][0], 0, 0, 0);
                acc[st][1] = __builtin_amdgcn_mfma_f32_16x16x32_bf16(af, bf1, acc[st][1], 0, 0, 0);
            }
        }
        __syncthreads();   // MFMA reads done before next stage overwrites
    }

    // epilogue: tanh, *u, reduce over this tile's 128 f-columns
    const float u0 = u[ft * 128 + wave * 32 + l16];
    const float u1 = u[ft * 128 + wave * 32 + 16 + l16];
    #pragma unroll
    for (int st = 0; st < 4; ++st) {
        float p[4];
        #pragma unroll
        for (int r = 0; r < 4; ++r)
            p[r] = tanhf(acc[st][0][r]) * u0 + tanhf(acc[st][1][r]) * u1;
        #pragma unroll
        for (int off = 8; off >= 1; off >>= 1)
            #pragma unroll
            for (int r = 0; r < 4; ++r)
                p[r] += __shfl_xor(p[r], off, 16);
        if (l16 == 0)
            #pragma unroll
            for (int r = 0; r < 4; ++r)
                s_red[wave][st * 16 + quad * 4 + r] = p[r];
    }
    __syncthreads();
    if (tid < 64) {
        const int strip = tid >> 4;
        if (val[strip]) {
            float v = s_red[0][tid] + s_red[1][tid] + s_red[2][tid] + s_red[3][tid];
            part[((size_t)(e[strip] + (tid & 15)) << 3) | ft] = v;
        }
    }
}

// ---------------------------------------------------------------------------
// Kernel 2 (fallback, small ws): in-kernel A conversion from fp32 x.
__launch_bounds__(256)
__global__ void scores_gemm_fb(const float* __restrict__ x,
                               const unsigned short* __restrict__ Wb,
                               const float* __restrict__ u,
                               const int* __restrict__ doc,
                               float* __restrict__ part) {
    __shared__ __align__(16) unsigned short As[8 * 16 * APAD];
    __shared__ __align__(16) unsigned short Bs[128 * BK];
    __shared__ float s_red[4][128];

    const int b  = blockIdx.x;
    const int ft = blockIdx.y;
    const int start = doc[2 * b], end = doc[2 * b + 1];
    const int strip0 = start >> 4;
    const int ns = ((end + 15) >> 4) - strip0;
    const int row0 = strip0 << 4;

    const int tid  = threadIdx.x;
    const int wave = tid >> 6;
    const int lane = tid & 63;
    const int quad = lane >> 4;
    const int l16  = lane & 15;
    const int arow = tid >> 4;
    const int acol = (tid & 15) << 2;

    const float* xbase = x + ((size_t)b * Ss + row0) * Ee;
    const unsigned short* wbase = Wb + (size_t)ft * 128 * Ee;

    f32x4 acc[8][2];
    #pragma unroll
    for (int i = 0; i < 8; ++i)
        #pragma unroll
        for (int j = 0; j < 2; ++j) acc[i][j] = (f32x4){0.f, 0.f, 0.f, 0.f};

    for (int k0 = 0; k0 < Ee; k0 += BK) {
        #pragma unroll
        for (int r = 0; r < 8; ++r) if (r < ns) {
            int row = (r << 4) | arow;
            float4 v = *reinterpret_cast<const float4*>(xbase + (size_t)row * Ee + k0 + acol);
            ushort4 o; o.x = f2bf(v.x); o.y = f2bf(v.y); o.z = f2bf(v.z); o.w = f2bf(v.w);
            *reinterpret_cast<ushort4*>(&As[row * APAD + acol]) = o;
        }
        #pragma unroll
        for (int r = 0; r < 4; ++r) {
            int chunk = (r << 8) | tid;
            int brow = chunk >> 3;
            int c8 = (chunk & 7) ^ (brow & 7);
            __builtin_amdgcn_global_load_lds(
                (const glb_u32*)(wbase + (size_t)brow * Ee + k0 + (c8 << 3)),
                (lds_u32*)&Bs[chunk << 3], 16, 0, 0);
        }
        __syncthreads();
        #pragma unroll
        for (int kk = 0; kk < BK; kk += 32) {
            const int n0 = wave * 32 + l16;
            const int n1 = n0 + 16;
            const int c8k = (kk >> 3) + quad;
            bf16x8 bf0 = *reinterpret_cast<const bf16x8*>(
                &Bs[((n0 << 3) | (c8k ^ (n0 & 7))) << 3]);
            bf16x8 bf1 = *reinterpret_cast<const bf16x8*>(
                &Bs[((n1 << 3) | (c8k ^ (n1 & 7))) << 3]);
            #pragma unroll
            for (int st = 0; st < 8; ++st) {
                if (st < ns) {
                    bf16x8 af = *reinterpret_cast<const bf16x8*>(
                        &As[(st * 16 + l16) * APAD + kk + quad * 8]);
                    acc[st][0] = __builtin_amdgcn_mfma_f32_16x16x32_bf16(af, bf0, acc[st][0], 0, 0, 0);
                    acc[st][1] = __builtin_amdgcn_mfma_f32_16x16x32_bf16(af, bf1, acc[st][1], 0, 0, 0);
                }
            }
        }
        __syncthreads();
    }

    const float u0 = u[ft * 128 + wave * 32 + l16];
    const float u1 = u[ft * 128 + wave * 32 + 16 + l16];
    #pragma unroll
    for (int st = 0; st < 8; ++st) {
        if (st < ns) {
            float p[4];
            #pragma unroll
            for (int r = 0; r < 4; ++r)
                p[r] = tanhf(acc[st][0][r]) * u0 + tanhf(acc[st][1][r]) * u1;
            #pragma unroll
            for (int off = 8; off >= 1; off >>= 1)
                #pragma unroll
                for (int r = 0; r < 4; ++r)
                    p[r] += __shfl_xor(p[r], off, 16);
            if (l16 == 0)
                #pragma unroll
                for (int r = 0; r < 4; ++r)
                    s_red[wave][st * 16 + quad * 4 + r] = p[r];
        }
    }
    __syncthreads();
    if (tid < (ns << 4)) {
        float v = s_red[0][tid] + s_red[1][tid] + s_red[2][tid] + s_red[3][tid];
        part[((size_t)(b * Ss + row0 + tid) << 3) | ft] = v;
    }
}

// ---------------------------------------------------------------------------
// Kernel 3: fused softmax + weighted sum. Grid (4 s-chunks of 32, Bb).
// Each block recomputes the bag softmax from part (1 KB), then accumulates
// its 32-row chunk of sum_s attn*x into out via fp32 atomics (out pre-zeroed,
// <=4 colliders/address). If xb != nullptr read bf16 xb, else fp32 x.
__global__ void out_fused(const unsigned short* __restrict__ xb,
                          const float* __restrict__ x,
                          const float* __restrict__ part,
                          const int* __restrict__ doc,
                          float* __restrict__ out,
                          float* __restrict__ keep) {
    const int c = blockIdx.x, b = blockIdx.y, t = threadIdx.x;
    const int start = doc[2 * b], end = doc[2 * b + 1];
    __shared__ float a_s[Ss];
    __shared__ float red[2];

    bool m = false;
    float sc = -INFINITY;
    if (t < Ss) {
        m = (t >= start) && (t < end);
        if (m) {
            const float4* p = reinterpret_cast<const float4*>(part + ((size_t)(b * Ss + t) << 3));
            float4 p0 = p[0], p1 = p[1];
            sc = ((p0.x + p0.y) + (p0.z + p0.w)) + ((p1.x + p1.y) + (p1.z + p1.w));
        }
    }
    float v = sc;
    #pragma unroll
    for (int off = 32; off >= 1; off >>= 1)
        v = fmaxf(v, __shfl_xor(v, off, 64));
    if (t < Ss && (t & 63) == 0) red[t >> 6] = v;
    __syncthreads();
    const float mx = fmaxf(red[0], red[1]);
    __syncthreads();
    const float e = m ? __expf(sc - mx) : 0.f;
    v = e;
    #pragma unroll
    for (int off = 32; off >= 1; off >>= 1)
        v += __shfl_xor(v, off, 64);
    if (t < Ss && (t & 63) == 0) red[t >> 6] = v;
    __syncthreads();
    if (t < Ss) a_s[t] = e / (red[0] + red[1]);
    __syncthreads();
    if (b == Bb - 1 && c == 0 && t < Ss) keep[t] = a_s[t];

    const int slo = max(start, c << 5), shi = min(end, (c << 5) + 32);
    if (slo >= shi) return;                 // block-uniform

    float4 accv = {0.f, 0.f, 0.f, 0.f};
    if (xb) {
        const unsigned short* xr = xb + (size_t)b * Ss * Ee;
        for (int s = slo; s < shi; ++s) {
            float a = a_s[s];
            ushort4 q = *reinterpret_cast<const ushort4*>(xr + (size_t)s * Ee + (t << 2));
            accv.x += a * bf2f(q.x); accv.y += a * bf2f(q.y);
            accv.z += a * bf2f(q.z); accv.w += a * bf2f(q.w);
        }
    } else {
        const float4* xr = reinterpret_cast<const float4*>(x + (size_t)b * Ss * Ee);
        for (int s = slo; s < shi; ++s) {
            float a = a_s[s];
            float4 q = xr[s * 256 + t];
            accv.x += a * q.x; accv.y += a * q.y;
            accv.z += a * q.z; accv.w += a * q.w;
        }
    }
    float* o = out + (size_t)b * Ee + (t << 2);
    atomicAdd(o + 0, accv.x);
    atomicAdd(o + 1, accv.y);
    atomicAdd(o + 2, accv.z);
    atomicAdd(o + 3, accv.w);
}

// ---------------------------------------------------------------------------
extern "C" void kernel_launch(void* const* d_in, const int* in_sizes, int n_in,
                              void* d_out, int out_size, void* d_ws, size_t ws_size,
                              hipStream_t stream) {
    const float* x  = (const float*)d_in[0];   // [B,S,E] f32
    const float* W  = (const float*)d_in[1];   // [E,E]   f32
    const float* u  = (const float*)d_in[2];   // [1,E]   f32
    const int* doc  = (const int*)d_in[3];     // [B,2]   i32
    float* out = (float*)d_out;                // [B*E] out_concat ++ [S] keep

    const size_t szWb   = (size_t)Ee * Ee * 2;          // 2 MB
    const size_t szXb   = (size_t)Bb * Ss * Ee * 2;     // 64 MB
    const size_t szPart = (size_t)Bb * Ss * 8 * 4;      // 1 MB
    const size_t szList = (size_t)NMAX * 4;             // 8 KB

    unsigned short* Wb = (unsigned short*)d_ws;
    const bool big_ws = ws_size >= szWb + szXb + szPart + szList;

    hipMemsetAsync(out, 0, (size_t)Bb * Ee * sizeof(float), stream);

    if (big_ws) {
        unsigned short* xbuf = (unsigned short*)((char*)d_ws + szWb);
        float* part = (float*)((char*)d_ws + szWb + szXb);
        int* list = (int*)((char*)d_ws + szWb + szXb + szPart);
        build_list<<<1, 256, 0, stream>>>(doc, list);
        conv_all<<<dim3(8, Bb + 128), 256, 0, stream>>>(x, W, doc, xbuf, Wb);
        scores_gemm_xb<<<dim3(NMAX / 4, 8), 256, 0, stream>>>(xbuf, Wb, u, list, part);
        out_fused<<<dim3(4, Bb), 256, 0, stream>>>(xbuf, x, part, doc, out, out + (size_t)Bb * Ee);
    } else {
        float* part = (float*)((char*)d_ws + szWb);
        convW_kernel<<<1024, 256, 0, stream>>>(W, Wb);
        scores_gemm_fb<<<dim3(Bb, 8), 256, 0, stream>>>(x, Wb, u, doc, part);
        out_fused<<<dim3(4, Bb), 256, 0, stream>>>(nullptr, x, part, doc, out, out + (size_t)Bb * Ee);
    }
}

// Round 7
// 245.557 us; speedup vs baseline: 1.3950x; 1.0645x over previous
//
#include <hip/hip_runtime.h>
#include <math.h>

// Problem constants (from reference): B=256, S=128, E=1024
#define Bb 256
#define Ss 128
#define Ee 1024
#define BK 64
#define APAD 72    // fallback-path A pad
#define NMAX 2048  // max strips (256 bags x 8)

typedef __bf16 bf16x8 __attribute__((ext_vector_type(8)));
typedef float f32x4 __attribute__((ext_vector_type(4)));

typedef __attribute__((address_space(3))) unsigned int lds_u32;
typedef __attribute__((address_space(1))) unsigned int glb_u32;

static __device__ __forceinline__ unsigned short f2bf(float f) {
    unsigned int u = __float_as_uint(f);
    u += 0x7FFFu + ((u >> 16) & 1u);
    return (unsigned short)(u >> 16);
}
static __device__ __forceinline__ float bf2f(unsigned short h) {
    return __uint_as_float((unsigned int)h << 16);
}

// ---------------------------------------------------------------------------
// Kernel 1: fused conversion + worklist. Grid (8, Bb+129).
//  by <  Bb       : convert covered 16-row strip `st` of bag `by` (f32->bf16)
//  Bb<=by<Bb+128  : convert a 1024-float4 slice of W (f32->bf16)
//  by == Bb+128   : (st==0 only) build the strip worklist
__global__ void conv_all(const float* __restrict__ x,
                         const float* __restrict__ W,
                         const int* __restrict__ doc,
                         unsigned short* __restrict__ xb,
                         unsigned short* __restrict__ Wb,
                         int* __restrict__ list) {
    const int st = blockIdx.x, by = blockIdx.y, tid = threadIdx.x;
    if (by == Bb + 128) {
        if (st != 0) return;
        __shared__ int sc[256];
        const int b = tid;
        const int start = doc[2 * b], end = doc[2 * b + 1];
        const int s0 = start >> 4;
        const int ns = ((end + 15) >> 4) - s0;
        sc[b] = ns;
        __syncthreads();
        for (int d = 1; d < 256; d <<= 1) {       // Hillis-Steele scan
            int v = sc[b];
            int add = (b >= d) ? sc[b - d] : 0;
            __syncthreads();
            sc[b] = v + add;
            __syncthreads();
        }
        const int total = sc[255];
        const int off = sc[b] - ns;
        for (int i = 0; i < ns; ++i)
            list[off + i] = b * Ss + ((s0 + i) << 4);
        for (int i = total + b; i < NMAX; i += 256)
            list[i] = -1;
        return;
    }
    if (by >= Bb) {
        int i = ((((by - Bb) << 3) | st) << 8) | tid;   // 1024 blocks x 256 f4
        float4 v = reinterpret_cast<const float4*>(W)[i];
        ushort4 o;
        o.x = f2bf(v.x); o.y = f2bf(v.y); o.z = f2bf(v.z); o.w = f2bf(v.w);
        reinterpret_cast<ushort4*>(Wb)[i] = o;
        return;
    }
    const int b = by;
    const int start = doc[2 * b], end = doc[2 * b + 1];
    const int strip0 = start >> 4;
    const int ns = ((end + 15) >> 4) - strip0;
    if (st < strip0 || st >= strip0 + ns) return;
    const size_t base = ((size_t)b * Ss + (st << 4)) * Ee;
    #pragma unroll
    for (int r = 0; r < 16; ++r) {
        size_t idx = base + (size_t)r * Ee + (tid << 2);
        float4 v = *reinterpret_cast<const float4*>(x + idx);
        ushort4 o;
        o.x = f2bf(v.x); o.y = f2bf(v.y); o.z = f2bf(v.z); o.w = f2bf(v.w);
        *reinterpret_cast<ushort4*>(xb + idx) = o;
    }
}

// Fallback W-only conversion (small ws path).
__global__ void convW_kernel(const float* __restrict__ W, unsigned short* __restrict__ Wb) {
    int i = blockIdx.x * blockDim.x + threadIdx.x;
    float4 v = reinterpret_cast<const float4*>(W)[i];
    ushort4 o;
    o.x = f2bf(v.x); o.y = f2bf(v.y); o.z = f2bf(v.z); o.w = f2bf(v.w);
    reinterpret_cast<ushort4*>(Wb)[i] = o;
}

// ---------------------------------------------------------------------------
// Kernel 2 (primary): compacted-strip scores GEMM, M=64 (4 strips) x N=256.
// Block (mb, fg): 4 waves, each wave owns 64 n-cols -> per kk: 4 A-reads +
// 4 B-reads + 16 MFMAs (ratio 2.0). LDS 40 KB -> 4 blocks/CU; acc 64 VGPRs.
// glds A+B, XOR-swizzled chunks (conflict-free, R3-verified).
// part layout: part[(b*Ss + s)*4 + fg].
__launch_bounds__(256, 4)
__global__ void scores_gemm_xb(const unsigned short* __restrict__ xb,
                               const unsigned short* __restrict__ Wb,
                               const float* __restrict__ u,
                               const int* __restrict__ list,
                               float* __restrict__ part) {
    __shared__ __align__(16) unsigned short As[64 * BK];     // 8 KB
    __shared__ __align__(16) unsigned short Bs[256 * BK];    // 32 KB

    const int mb = blockIdx.x;          // mb fastest: same W slice chip-wide
    const int fg = blockIdx.y;          // f-group of 256 cols

    int e0 = list[mb << 2];
    if (e0 < 0) return;                 // fully-padded block
    int e[4];
    bool val[4];
    e[0] = e0; val[0] = true;
    #pragma unroll
    for (int j = 1; j < 4; ++j) {
        int v = list[(mb << 2) | j];
        val[j] = v >= 0;
        e[j] = val[j] ? v : e0;         // clamp padding to a valid strip
    }

    const int tid  = threadIdx.x;
    const int wave = tid >> 6;
    const int lane = tid & 63;
    const int quad = lane >> 4;
    const int l16  = lane & 15;

    const unsigned short* wbase = Wb + (size_t)(fg * 256) * Ee;

    f32x4 acc[4][4];   // [strip][nfrag]
    #pragma unroll
    for (int i = 0; i < 4; ++i)
        #pragma unroll
        for (int j = 0; j < 4; ++j) acc[i][j] = (f32x4){0.f, 0.f, 0.f, 0.f};

    for (int t = 0; t < 16; ++t) {
        const int k0 = t << 6;
        // stage A: 512 chunks of 16B (4 strips x 16 rows x 8 c8-groups)
        #pragma unroll
        for (int r = 0; r < 2; ++r) {
            int chunk = (r << 8) | tid;
            int arow = chunk >> 3;            // 0..63
            int c8 = (chunk & 7) ^ (arow & 7);
            __builtin_amdgcn_global_load_lds(
                (const glb_u32*)(xb + ((size_t)e[arow >> 4] + (arow & 15)) * Ee + k0 + (c8 << 3)),
                (lds_u32*)&As[chunk << 3], 16, 0, 0);
        }
        // stage B: 2048 chunks of 16B (256 f-rows x 8 c8-groups)
        #pragma unroll
        for (int r = 0; r < 8; ++r) {
            int chunk = (r << 8) | tid;
            int brow = chunk >> 3;
            int c8 = (chunk & 7) ^ (brow & 7);
            __builtin_amdgcn_global_load_lds(
                (const glb_u32*)(wbase + (size_t)brow * Ee + k0 + (c8 << 3)),
                (lds_u32*)&Bs[chunk << 3], 16, 0, 0);
        }
        __syncthreads();

        #pragma unroll
        for (int kk = 0; kk < BK; kk += 32) {
            const int c8k = (kk >> 3) + quad;
            bf16x8 bf[4];
            #pragma unroll
            for (int j = 0; j < 4; ++j) {
                const int n = wave * 64 + j * 16 + l16;
                bf[j] = *reinterpret_cast<const bf16x8*>(
                    &Bs[((n << 3) | (c8k ^ (n & 7))) << 3]);
            }
            #pragma unroll
            for (int st = 0; st < 4; ++st) {
                const int ar = st * 16 + l16;
                bf16x8 af = *reinterpret_cast<const bf16x8*>(
                    &As[((ar << 3) | (c8k ^ (ar & 7))) << 3]);
                #pragma unroll
                for (int j = 0; j < 4; ++j)
                    acc[st][j] = __builtin_amdgcn_mfma_f32_16x16x32_bf16(af, bf[j], acc[st][j], 0, 0, 0);
            }
        }
        __syncthreads();   // MFMA reads done before next stage overwrites
    }

    // epilogue: tanh, *u, reduce this block's 256 f-cols. s_red aliases As.
    float* s_red = reinterpret_cast<float*>(As);   // 4 waves x 64 floats
    float uj[4];
    #pragma unroll
    for (int j = 0; j < 4; ++j)
        uj[j] = u[fg * 256 + wave * 64 + j * 16 + l16];
    #pragma unroll
    for (int st = 0; st < 4; ++st) {
        float p[4];
        #pragma unroll
        for (int r = 0; r < 4; ++r) {
            p[r] = tanhf(acc[st][0][r]) * uj[0] + tanhf(acc[st][1][r]) * uj[1]
                 + tanhf(acc[st][2][r]) * uj[2] + tanhf(acc[st][3][r]) * uj[3];
        }
        #pragma unroll
        for (int off = 8; off >= 1; off >>= 1)
            #pragma unroll
            for (int r = 0; r < 4; ++r)
                p[r] += __shfl_xor(p[r], off, 16);
        if (l16 == 0)
            #pragma unroll
            for (int r = 0; r < 4; ++r)
                s_red[wave * 64 + st * 16 + quad * 4 + r] = p[r];
    }
    __syncthreads();
    if (tid < 64) {
        const int strip = tid >> 4;
        if (val[strip]) {
            float v = s_red[tid] + s_red[64 + tid] + s_red[128 + tid] + s_red[192 + tid];
            part[(((size_t)e[strip] + (tid & 15)) << 2) | fg] = v;
        }
    }
}

// ---------------------------------------------------------------------------
// Kernel 2 (fallback, small ws): in-kernel A conversion from fp32 x.
// part layout here: part[(b*Ss + s)*8 + ft] (np8 path in out_fused).
__launch_bounds__(256)
__global__ void scores_gemm_fb(const float* __restrict__ x,
                               const unsigned short* __restrict__ Wb,
                               const float* __restrict__ u,
                               const int* __restrict__ doc,
                               float* __restrict__ part) {
    __shared__ __align__(16) unsigned short As[8 * 16 * APAD];
    __shared__ __align__(16) unsigned short Bs[128 * BK];
    __shared__ float s_red[4][128];

    const int b  = blockIdx.x;
    const int ft = blockIdx.y;
    const int start = doc[2 * b], end = doc[2 * b + 1];
    const int strip0 = start >> 4;
    const int ns = ((end + 15) >> 4) - strip0;
    const int row0 = strip0 << 4;

    const int tid  = threadIdx.x;
    const int wave = tid >> 6;
    const int lane = tid & 63;
    const int quad = lane >> 4;
    const int l16  = lane & 15;
    const int arow = tid >> 4;
    const int acol = (tid & 15) << 2;

    const float* xbase = x + ((size_t)b * Ss + row0) * Ee;
    const unsigned short* wbase = Wb + (size_t)ft * 128 * Ee;

    f32x4 acc[8][2];
    #pragma unroll
    for (int i = 0; i < 8; ++i)
        #pragma unroll
        for (int j = 0; j < 2; ++j) acc[i][j] = (f32x4){0.f, 0.f, 0.f, 0.f};

    for (int k0 = 0; k0 < Ee; k0 += BK) {
        #pragma unroll
        for (int r = 0; r < 8; ++r) if (r < ns) {
            int row = (r << 4) | arow;
            float4 v = *reinterpret_cast<const float4*>(xbase + (size_t)row * Ee + k0 + acol);
            ushort4 o; o.x = f2bf(v.x); o.y = f2bf(v.y); o.z = f2bf(v.z); o.w = f2bf(v.w);
            *reinterpret_cast<ushort4*>(&As[row * APAD + acol]) = o;
        }
        #pragma unroll
        for (int r = 0; r < 4; ++r) {
            int chunk = (r << 8) | tid;
            int brow = chunk >> 3;
            int c8 = (chunk & 7) ^ (brow & 7);
            __builtin_amdgcn_global_load_lds(
                (const glb_u32*)(wbase + (size_t)brow * Ee + k0 + (c8 << 3)),
                (lds_u32*)&Bs[chunk << 3], 16, 0, 0);
        }
        __syncthreads();
        #pragma unroll
        for (int kk = 0; kk < BK; kk += 32) {
            const int n0 = wave * 32 + l16;
            const int n1 = n0 + 16;
            const int c8k = (kk >> 3) + quad;
            bf16x8 bf0 = *reinterpret_cast<const bf16x8*>(
                &Bs[((n0 << 3) | (c8k ^ (n0 & 7))) << 3]);
            bf16x8 bf1 = *reinterpret_cast<const bf16x8*>(
                &Bs[((n1 << 3) | (c8k ^ (n1 & 7))) << 3]);
            #pragma unroll
            for (int st = 0; st < 8; ++st) {
                if (st < ns) {
                    bf16x8 af = *reinterpret_cast<const bf16x8*>(
                        &As[(st * 16 + l16) * APAD + kk + quad * 8]);
                    acc[st][0] = __builtin_amdgcn_mfma_f32_16x16x32_bf16(af, bf0, acc[st][0], 0, 0, 0);
                    acc[st][1] = __builtin_amdgcn_mfma_f32_16x16x32_bf16(af, bf1, acc[st][1], 0, 0, 0);
                }
            }
        }
        __syncthreads();
    }

    const float u0 = u[ft * 128 + wave * 32 + l16];
    const float u1 = u[ft * 128 + wave * 32 + 16 + l16];
    #pragma unroll
    for (int st = 0; st < 8; ++st) {
        if (st < ns) {
            float p[4];
            #pragma unroll
            for (int r = 0; r < 4; ++r)
                p[r] = tanhf(acc[st][0][r]) * u0 + tanhf(acc[st][1][r]) * u1;
            #pragma unroll
            for (int off = 8; off >= 1; off >>= 1)
                #pragma unroll
                for (int r = 0; r < 4; ++r)
                    p[r] += __shfl_xor(p[r], off, 16);
            if (l16 == 0)
                #pragma unroll
                for (int r = 0; r < 4; ++r)
                    s_red[wave][st * 16 + quad * 4 + r] = p[r];
        }
    }
    __syncthreads();
    if (tid < (ns << 4)) {
        float v = s_red[0][tid] + s_red[1][tid] + s_red[2][tid] + s_red[3][tid];
        part[((size_t)(b * Ss + row0 + tid) << 3) | ft] = v;
    }
}

// ---------------------------------------------------------------------------
// Kernel 3: fused softmax + weighted sum, non-atomic. Grid (4 e-quarters, Bb).
// Block (h,b) owns out[b][h*256..+256): 4 s-subsets x 64 threads, LDS merge.
// No memset needed. np8: part stride 8 (fallback) vs 4 (primary).
__global__ void out_fused(const unsigned short* __restrict__ xb,
                          const float* __restrict__ x,
                          const float* __restrict__ part,
                          const int* __restrict__ doc,
                          float* __restrict__ out,
                          float* __restrict__ keep,
                          int np8) {
    const int h = blockIdx.x, b = blockIdx.y, t = threadIdx.x;
    const int start = doc[2 * b], end = doc[2 * b + 1];
    __shared__ float a_s[Ss];
    __shared__ float red[2];
    __shared__ float4 red4[4][64];

    bool m = false;
    float sc = -INFINITY;
    if (t < Ss) {
        m = (t >= start) && (t < end);
        if (m) {
            const float* pp = part + (size_t)(b * Ss + t) * (np8 ? 8 : 4);
            float4 p0 = *reinterpret_cast<const float4*>(pp);
            sc = (p0.x + p0.y) + (p0.z + p0.w);
            if (np8) {
                float4 p1 = *reinterpret_cast<const float4*>(pp + 4);
                sc += (p1.x + p1.y) + (p1.z + p1.w);
            }
        }
    }
    float v = sc;
    #pragma unroll
    for (int off = 32; off >= 1; off >>= 1)
        v = fmaxf(v, __shfl_xor(v, off, 64));
    if (t < Ss && (t & 63) == 0) red[t >> 6] = v;
    __syncthreads();
    const float mx = fmaxf(red[0], red[1]);
    __syncthreads();
    const float e = m ? __expf(sc - mx) : 0.f;
    v = e;
    #pragma unroll
    for (int off = 32; off >= 1; off >>= 1)
        v += __shfl_xor(v, off, 64);
    if (t < Ss && (t & 63) == 0) red[t >> 6] = v;
    __syncthreads();
    if (t < Ss) a_s[t] = e / (red[0] + red[1]);
    __syncthreads();
    if (h == 0 && b == Bb - 1 && t < Ss) keep[t] = a_s[t];

    const int ssub = t >> 6, tt = t & 63;
    float4 accv = {0.f, 0.f, 0.f, 0.f};
    if (xb) {
        const unsigned short* xr = xb + (size_t)b * Ss * Ee + h * 256 + (tt << 2);
        for (int s = start + ssub; s < end; s += 4) {
            float a = a_s[s];
            ushort4 q = *reinterpret_cast<const ushort4*>(xr + (size_t)s * Ee);
            accv.x += a * bf2f(q.x); accv.y += a * bf2f(q.y);
            accv.z += a * bf2f(q.z); accv.w += a * bf2f(q.w);
        }
    } else {
        const float* xr = x + (size_t)b * Ss * Ee + h * 256 + (tt << 2);
        for (int s = start + ssub; s < end; s += 4) {
            float a = a_s[s];
            float4 q = *reinterpret_cast<const float4*>(xr + (size_t)s * Ee);
            accv.x += a * q.x; accv.y += a * q.y;
            accv.z += a * q.z; accv.w += a * q.w;
        }
    }
    red4[ssub][tt] = accv;
    __syncthreads();
    if (t < 64) {
        float4 r0 = red4[0][t], r1 = red4[1][t], r2 = red4[2][t], r3 = red4[3][t];
        float4 s;
        s.x = (r0.x + r1.x) + (r2.x + r3.x);
        s.y = (r0.y + r1.y) + (r2.y + r3.y);
        s.z = (r0.z + r1.z) + (r2.z + r3.z);
        s.w = (r0.w + r1.w) + (r2.w + r3.w);
        reinterpret_cast<float4*>(out + (size_t)b * Ee + h * 256)[t] = s;
    }
}

// ---------------------------------------------------------------------------
extern "C" void kernel_launch(void* const* d_in, const int* in_sizes, int n_in,
                              void* d_out, int out_size, void* d_ws, size_t ws_size,
                              hipStream_t stream) {
    const float* x  = (const float*)d_in[0];   // [B,S,E] f32
    const float* W  = (const float*)d_in[1];   // [E,E]   f32
    const float* u  = (const float*)d_in[2];   // [1,E]   f32
    const int* doc  = (const int*)d_in[3];     // [B,2]   i32
    float* out = (float*)d_out;                // [B*E] out_concat ++ [S] keep

    const size_t szWb   = (size_t)Ee * Ee * 2;          // 2 MB
    const size_t szXb   = (size_t)Bb * Ss * Ee * 2;     // 64 MB
    const size_t szPart = (size_t)Bb * Ss * 8 * 4;      // 1 MB (covers both strides)
    const size_t szList = (size_t)NMAX * 4;             // 8 KB

    unsigned short* Wb = (unsigned short*)d_ws;
    const bool big_ws = ws_size >= szWb + szXb + szPart + szList;

    if (big_ws) {
        unsigned short* xbuf = (unsigned short*)((char*)d_ws + szWb);
        float* part = (float*)((char*)d_ws + szWb + szXb);
        int* list = (int*)((char*)d_ws + szWb + szXb + szPart);
        conv_all<<<dim3(8, Bb + 129), 256, 0, stream>>>(x, W, doc, xbuf, Wb, list);
        scores_gemm_xb<<<dim3(NMAX / 4, 4), 256, 0, stream>>>(xbuf, Wb, u, list, part);
        out_fused<<<dim3(4, Bb), 256, 0, stream>>>(xbuf, x, part, doc, out, out + (size_t)Bb * Ee, 0);
    } else {
        float* part = (float*)((char*)d_ws + szWb);
        convW_kernel<<<1024, 256, 0, stream>>>(W, Wb);
        scores_gemm_fb<<<dim3(Bb, 8), 256, 0, stream>>>(x, Wb, u, doc, part);
        out_fused<<<dim3(4, Bb), 256, 0, stream>>>(nullptr, x, part, doc, out, out + (size_t)Bb * Ee, 1);
    }
}